// Round 1
// baseline (1666.833 us; speedup 1.0000x reference)
//
#include <hip/hip_runtime.h>

#define HEADS 4
#define CH 64
#define HC 256   // HEADS*CH
#define NEG 0.2f

// monotone float<->uint encoding for atomicMax-based segment max
__device__ __forceinline__ unsigned fenc(float f){
  unsigned u = __float_as_uint(f);
  return (u & 0x80000000u) ? ~u : (u | 0x80000000u);
}
__device__ __forceinline__ float fdec(unsigned k){
  return (k & 0x80000000u) ? __uint_as_float(k & 0x7fffffffu) : __uint_as_float(~k);
}

// h = x @ W  -> hproj [N, H*C]; a_s[n,h] = sum_c h*att_src ; a_d likewise.
// Block = 256 threads; wave w handles head w (64 channels); NB nodes/block.
template<int FIN, int NB>
__global__ __launch_bounds__(256)
void proj_kernel(const float* __restrict__ x, const float* __restrict__ W,
                 const float* __restrict__ att_src, const float* __restrict__ att_dst,
                 float* __restrict__ hproj, float* __restrict__ a_s, float* __restrict__ a_d,
                 int N)
{
  __shared__ float xs[NB][FIN];
  const int t = threadIdx.x;
  const int n0 = blockIdx.x * NB;
  for (int i = t; i < NB*FIN; i += 256){
    int n = n0 + i / FIN;
    xs[i/FIN][i%FIN] = (n < N) ? x[(size_t)n*FIN + (i % FIN)] : 0.f;
  }
  __syncthreads();
  const int lane = t & 63;
  const int head = t >> 6;
  const int col  = head*CH + lane;
  float wcol[FIN];
#pragma unroll
  for (int k = 0; k < FIN; ++k) wcol[k] = W[(size_t)k*HC + col];
  const float attS = att_src[col];
  const float attD = att_dst[col];
  for (int i = 0; i < NB; ++i){
    int n = n0 + i;
    if (n >= N) break;
    float acc = 0.f;
#pragma unroll
    for (int k = 0; k < FIN; ++k) acc += xs[i][k] * wcol[k];
    hproj[(size_t)n*HC + col] = acc;
    float ps = acc*attS, pd = acc*attD;
#pragma unroll
    for (int off = 32; off; off >>= 1){
      ps += __shfl_down(ps, off);
      pd += __shfl_down(pd, off);
    }
    if (lane == 0){ a_s[n*HEADS + head] = ps; a_d[n*HEADS + head] = pd; }
  }
}

// Edge pass A: segment max of leaky_relu(a_s[src]+a_d[dst]) over dst.
__global__ __launch_bounds__(256)
void edge_max_kernel(const int* __restrict__ esrc, const int* __restrict__ edst,
                     int E, int N,
                     const float* __restrict__ a_s, const float* __restrict__ a_d,
                     unsigned* __restrict__ m_enc)
{
  int e = blockIdx.x*256 + threadIdx.x;
  int Etot = E + N;
  if (e >= Etot) return;
  int s, d;
  if (e < E){ s = esrc[e]; d = edst[e]; } else { s = d = e - E; }
  const float4 as = *(const float4*)(a_s + (size_t)s*4);
  const float4 ad = *(const float4*)(a_d + (size_t)d*4);
  float ev[4] = {as.x+ad.x, as.y+ad.y, as.z+ad.z, as.w+ad.w};
#pragma unroll
  for (int h = 0; h < 4; ++h){
    float v = ev[h] > 0.f ? ev[h] : NEG*ev[h];
    atomicMax(m_enc + (size_t)d*4 + h, fenc(v));
  }
}

// Edge pass B: den[dst,h] += exp(e - m[dst,h])
__global__ __launch_bounds__(256)
void edge_den_kernel(const int* __restrict__ esrc, const int* __restrict__ edst,
                     int E, int N,
                     const float* __restrict__ a_s, const float* __restrict__ a_d,
                     const unsigned* __restrict__ m_enc, float* __restrict__ den)
{
  int e = blockIdx.x*256 + threadIdx.x;
  int Etot = E + N;
  if (e >= Etot) return;
  int s, d;
  if (e < E){ s = esrc[e]; d = edst[e]; } else { s = d = e - E; }
  const float4 as = *(const float4*)(a_s + (size_t)s*4);
  const float4 ad = *(const float4*)(a_d + (size_t)d*4);
  float ev[4] = {as.x+ad.x, as.y+ad.y, as.z+ad.z, as.w+ad.w};
#pragma unroll
  for (int h = 0; h < 4; ++h){
    float v = ev[h] > 0.f ? ev[h] : NEG*ev[h];
    float ex = expf(v - fdec(m_enc[(size_t)d*4 + h]));
    atomicAdd(den + (size_t)d*4 + h, ex);
  }
}

// Edge pass C: wave per edge, lane = channel.
// accum[dst,c] += (1/H) * sum_h alpha_h * hproj[src,h,c]
__global__ __launch_bounds__(256)
void edge_accum_kernel(const int* __restrict__ esrc, const int* __restrict__ edst,
                       int E, int N,
                       const float* __restrict__ a_s, const float* __restrict__ a_d,
                       const unsigned* __restrict__ m_enc, const float* __restrict__ den,
                       const float* __restrict__ hproj, float* __restrict__ accum)
{
  int wid  = (blockIdx.x*256 + threadIdx.x) >> 6;
  int lane = threadIdx.x & 63;
  int Etot = E + N;
  if (wid >= Etot) return;
  int s, d;
  if (wid < E){ s = esrc[wid]; d = edst[wid]; } else { s = d = wid - E; }
  float val = 0.f;
#pragma unroll
  for (int h = 0; h < 4; ++h){
    float e = a_s[(size_t)s*4 + h] + a_d[(size_t)d*4 + h];
    e = e > 0.f ? e : NEG*e;
    float ex = expf(e - fdec(m_enc[(size_t)d*4 + h]));
    float alpha = ex / den[(size_t)d*4 + h];
    val += alpha * hproj[(size_t)s*HC + h*CH + lane];
  }
  atomicAdd(accum + (size_t)d*CH + lane, 0.25f*val);
}

// feat = relu(accum + bias)
__global__ __launch_bounds__(256)
void node_finish_kernel(const float* __restrict__ accum, const float* __restrict__ bias,
                        float* __restrict__ feat, int N)
{
  int i = blockIdx.x*256 + threadIdx.x;
  if (i >= N*CH) return;
  float v = accum[i] + bias[i & 63];
  feat[i] = fmaxf(v, 0.f);
}

// global mean pool (sums + counts)
__global__ __launch_bounds__(256)
void pool_kernel(const float* __restrict__ feat, const int* __restrict__ batch,
                 float* __restrict__ pools, float* __restrict__ cnts, int N)
{
  int i = blockIdx.x*256 + threadIdx.x;
  if (i >= N*CH) return;
  int n = i >> 6, c = i & 63;
  int g = batch[n];
  atomicAdd(pools + (size_t)g*CH + c, feat[i]);
  if (c == 0) atomicAdd(cnts + g, 1.f);
}

// per-graph MLP: 64 threads/block, block = graph
__global__ __launch_bounds__(64)
void mlp_kernel(const float* __restrict__ pools, const float* __restrict__ cnts,
                const float* __restrict__ Wp1, const float* __restrict__ bp1,
                const float* __restrict__ Wp2, const float* __restrict__ bp2,
                float* __restrict__ out, int G)
{
  int g = blockIdx.x;
  int t = threadIdx.x;
  __shared__ float pooled[CH];
  float inv = 1.f / fmaxf(cnts[g], 1.f);
  pooled[t] = pools[(size_t)g*CH + t] * inv;
  __syncthreads();
  float hid = 0.f;
  if (t < 32){
    float acc = bp1[t];
#pragma unroll
    for (int k = 0; k < CH; ++k) acc += pooled[k] * Wp1[k*32 + t];
    hid = fmaxf(acc, 0.f) * Wp2[t];
  }
#pragma unroll
  for (int off = 32; off; off >>= 1) hid += __shfl_down(hid, off);
  if (t == 0) out[g] = hid + bp2[0];
}

extern "C" void kernel_launch(void* const* d_in, const int* in_sizes, int n_in,
                              void* d_out, int out_size, void* d_ws, size_t ws_size,
                              hipStream_t stream)
{
  const float* x   = (const float*)d_in[0];
  const int*   ei  = (const int*)d_in[1];
  const int*   bat = (const int*)d_in[2];
  // d_in[3] = num_graphs (scalar on device; we use out_size instead)
  const float* W1  = (const float*)d_in[4];
  const float* as1 = (const float*)d_in[5];
  const float* ad1 = (const float*)d_in[6];
  const float* b1  = (const float*)d_in[7];
  const float* W2  = (const float*)d_in[8];
  const float* as2 = (const float*)d_in[9];
  const float* ad2 = (const float*)d_in[10];
  const float* b2  = (const float*)d_in[11];
  const float* Wp1 = (const float*)d_in[12];
  const float* bp1 = (const float*)d_in[13];
  const float* Wp2 = (const float*)d_in[14];
  const float* bp2 = (const float*)d_in[15];

  const int N = in_sizes[0] / 8;     // x is [N, 8]
  const int E = in_sizes[1] / 2;     // edge_index is [2, E]
  const int G = out_size;            // output is [G, 1]
  const int Etot = E + N;
  const int* esrc = ei;
  const int* edst = ei + E;

  float* ws = (float*)d_ws;
  size_t o = 0;
  float*    hproj = ws + o; o += (size_t)N*HC;
  float*    a_s   = ws + o; o += (size_t)N*HEADS;
  float*    a_d   = ws + o; o += (size_t)N*HEADS;
  unsigned* m_enc = (unsigned*)(ws + o); o += (size_t)N*HEADS;
  float*    den   = ws + o; o += (size_t)N*HEADS;
  float*    accum = ws + o; o += (size_t)N*CH;
  float*    feat  = ws + o; o += (size_t)N*CH;
  float*    pools = ws + o; o += (size_t)G*CH;
  float*    cnts  = ws + o; o += (size_t)G;

  const int eb = (Etot + 255) / 256;          // edge kernels, thread/edge
  const int ab = (Etot + 3) / 4;              // edge_accum, wave/edge, 4 waves/block
  const int nb = (N*CH + 255) / 256;          // node-feature kernels

  // ---------------- layer 1 (Fin = 8) ----------------
  hipMemsetAsync(m_enc, 0, (size_t)N*HEADS*sizeof(unsigned), stream);
  hipMemsetAsync(den,   0, (size_t)N*HEADS*sizeof(float), stream);
  hipMemsetAsync(accum, 0, (size_t)N*CH*sizeof(float), stream);
  proj_kernel<8,8><<<(N+7)/8, 256, 0, stream>>>(x, W1, as1, ad1, hproj, a_s, a_d, N);
  edge_max_kernel<<<eb, 256, 0, stream>>>(esrc, edst, E, N, a_s, a_d, m_enc);
  edge_den_kernel<<<eb, 256, 0, stream>>>(esrc, edst, E, N, a_s, a_d, m_enc, den);
  edge_accum_kernel<<<ab, 256, 0, stream>>>(esrc, edst, E, N, a_s, a_d, m_enc, den, hproj, accum);
  node_finish_kernel<<<nb, 256, 0, stream>>>(accum, b1, feat, N);

  // ---------------- layer 2 (Fin = 64) ----------------
  hipMemsetAsync(m_enc, 0, (size_t)N*HEADS*sizeof(unsigned), stream);
  hipMemsetAsync(den,   0, (size_t)N*HEADS*sizeof(float), stream);
  hipMemsetAsync(accum, 0, (size_t)N*CH*sizeof(float), stream);
  proj_kernel<64,8><<<(N+7)/8, 256, 0, stream>>>(feat, W2, as2, ad2, hproj, a_s, a_d, N);
  edge_max_kernel<<<eb, 256, 0, stream>>>(esrc, edst, E, N, a_s, a_d, m_enc);
  edge_den_kernel<<<eb, 256, 0, stream>>>(esrc, edst, E, N, a_s, a_d, m_enc, den);
  edge_accum_kernel<<<ab, 256, 0, stream>>>(esrc, edst, E, N, a_s, a_d, m_enc, den, hproj, accum);
  node_finish_kernel<<<nb, 256, 0, stream>>>(accum, b2, feat, N);

  // ---------------- pool + MLP ----------------
  hipMemsetAsync(pools, 0, (size_t)(G*CH + G)*sizeof(float), stream); // pools + cnts contiguous
  pool_kernel<<<nb, 256, 0, stream>>>(feat, bat, pools, cnts, N);
  mlp_kernel<<<G, 64, 0, stream>>>(pools, cnts, Wp1, bp1, Wp2, bp2, (float*)d_out, G);
}

// Round 2
// 1018.253 us; speedup vs baseline: 1.6370x; 1.6370x over previous
//
#include <hip/hip_runtime.h>

#define HEADS 4
#define CH 64
#define HC 256   // HEADS*CH
#define NEG 0.2f

// h = x @ W  -> hproj [N, H*C]; a_s[n,h] = sum_c h*att_src ; a_d likewise.
// Block = 256 threads; wave w handles head w (64 channels); NB nodes/block.
template<int FIN, int NB>
__global__ __launch_bounds__(256)
void proj_kernel(const float* __restrict__ x, const float* __restrict__ W,
                 const float* __restrict__ att_src, const float* __restrict__ att_dst,
                 float* __restrict__ hproj, float* __restrict__ a_s, float* __restrict__ a_d,
                 int N)
{
  __shared__ float xs[NB][FIN];
  const int t = threadIdx.x;
  const int n0 = blockIdx.x * NB;
  for (int i = t; i < NB*FIN; i += 256){
    int n = n0 + i / FIN;
    xs[i/FIN][i%FIN] = (n < N) ? x[(size_t)n*FIN + (i % FIN)] : 0.f;
  }
  __syncthreads();
  const int lane = t & 63;
  const int head = t >> 6;
  const int col  = head*CH + lane;
  float wcol[FIN];
#pragma unroll
  for (int k = 0; k < FIN; ++k) wcol[k] = W[(size_t)k*HC + col];
  const float attS = att_src[col];
  const float attD = att_dst[col];
  for (int i = 0; i < NB; ++i){
    int n = n0 + i;
    if (n >= N) break;
    float acc = 0.f;
#pragma unroll
    for (int k = 0; k < FIN; ++k) acc += xs[i][k] * wcol[k];
    hproj[(size_t)n*HC + col] = acc;
    float ps = acc*attS, pd = acc*attD;
#pragma unroll
    for (int off = 32; off; off >>= 1){
      ps += __shfl_down(ps, off);
      pd += __shfl_down(pd, off);
    }
    if (lane == 0){ a_s[n*HEADS + head] = ps; a_d[n*HEADS + head] = pd; }
  }
}

// Edge pass A: den[dst,h] += exp(leaky(a_s[src]+a_d[dst]))   (no max shift; logits are O(1))
__global__ __launch_bounds__(256)
void edge_den_kernel(const int* __restrict__ esrc, const int* __restrict__ edst,
                     int E, int N,
                     const float* __restrict__ a_s, const float* __restrict__ a_d,
                     float* __restrict__ den)
{
  int e = blockIdx.x*256 + threadIdx.x;
  int Etot = E + N;
  if (e >= Etot) return;
  int s, d;
  if (e < E){ s = esrc[e]; d = edst[e]; } else { s = d = e - E; }
  const float4 as = *(const float4*)(a_s + (size_t)s*4);
  const float4 ad = *(const float4*)(a_d + (size_t)d*4);
  float ev[4] = {as.x+ad.x, as.y+ad.y, as.z+ad.z, as.w+ad.w};
#pragma unroll
  for (int h = 0; h < 4; ++h){
    float v = ev[h] > 0.f ? ev[h] : NEG*ev[h];
    atomicAdd(den + (size_t)d*4 + h, expf(v));
  }
}

// Edge pass B: wave per edge, lane = channel.
// accum[dst,c] += (1/H) * sum_h alpha_h * hproj[src,h,c],  alpha = exp(e)/den
__global__ __launch_bounds__(256)
void edge_accum_kernel(const int* __restrict__ esrc, const int* __restrict__ edst,
                       int E, int N,
                       const float* __restrict__ a_s, const float* __restrict__ a_d,
                       const float* __restrict__ den,
                       const float* __restrict__ hproj, float* __restrict__ accum)
{
  int wid  = (blockIdx.x*256 + threadIdx.x) >> 6;
  int lane = threadIdx.x & 63;
  int Etot = E + N;
  if (wid >= Etot) return;
  int s, d;
  if (wid < E){ s = esrc[wid]; d = edst[wid]; } else { s = d = wid - E; }
  float val = 0.f;
#pragma unroll
  for (int h = 0; h < 4; ++h){
    float e = a_s[(size_t)s*4 + h] + a_d[(size_t)d*4 + h];
    e = e > 0.f ? e : NEG*e;
    float alpha = expf(e) / den[(size_t)d*4 + h];
    val += alpha * hproj[(size_t)s*HC + h*CH + lane];
  }
  atomicAdd(accum + (size_t)d*CH + lane, 0.25f*val);
}

// feat = relu(accum + bias)   (layer-1 only; layer-2 finish is fused into pool_mlp)
__global__ __launch_bounds__(256)
void node_finish_kernel(const float* __restrict__ accum, const float* __restrict__ bias,
                        float* __restrict__ feat, int N)
{
  int i = blockIdx.x*256 + threadIdx.x;
  if (i >= N*CH) return;
  float v = accum[i] + bias[i & 63];
  feat[i] = fmaxf(v, 0.f);
}

// Fused: bias+relu of layer-2 accum -> per-graph mean pool (batch sorted, binary
// search segment bounds; no atomics) -> 64->32->1 MLP. One block per graph.
__global__ __launch_bounds__(256)
void pool_mlp_kernel(const float* __restrict__ accum, const float* __restrict__ bias,
                     const int* __restrict__ batch, int N,
                     const float* __restrict__ Wp1, const float* __restrict__ bp1,
                     const float* __restrict__ Wp2, const float* __restrict__ bp2,
                     float* __restrict__ out)
{
  const int g = blockIdx.x;
  __shared__ int seg[2];
  __shared__ float part[256];
  __shared__ float pooled[CH];
  if (threadIdx.x < 2){
    int target = g + (int)threadIdx.x;
    int lo = 0, hi = N;
    while (lo < hi){ int mid = (lo + hi) >> 1; if (batch[mid] < target) lo = mid + 1; else hi = mid; }
    seg[threadIdx.x] = lo;
  }
  __syncthreads();
  const int start = seg[0], end = seg[1];
  const int c = threadIdx.x & 63, w = threadIdx.x >> 6;
  float acc = 0.f;
  const float bc = bias[c];
  for (int n = start + w; n < end; n += 4)
    acc += fmaxf(accum[(size_t)n*CH + c] + bc, 0.f);
  part[threadIdx.x] = acc;
  __syncthreads();
  if (threadIdx.x < CH){
    float s = part[threadIdx.x] + part[threadIdx.x+64] + part[threadIdx.x+128] + part[threadIdx.x+192];
    pooled[threadIdx.x] = s / fmaxf((float)(end - start), 1.f);
  }
  __syncthreads();
  float hid = 0.f;
  if (threadIdx.x < 32){
    float a2 = bp1[threadIdx.x];
#pragma unroll
    for (int k = 0; k < CH; ++k) a2 += pooled[k] * Wp1[k*32 + threadIdx.x];
    hid = fmaxf(a2, 0.f) * Wp2[threadIdx.x];
  }
#pragma unroll
  for (int off = 16; off; off >>= 1) hid += __shfl_down(hid, off);
  if (threadIdx.x == 0) out[g] = hid + bp2[0];
}

extern "C" void kernel_launch(void* const* d_in, const int* in_sizes, int n_in,
                              void* d_out, int out_size, void* d_ws, size_t ws_size,
                              hipStream_t stream)
{
  const float* x   = (const float*)d_in[0];
  const int*   ei  = (const int*)d_in[1];
  const int*   bat = (const int*)d_in[2];
  const float* W1  = (const float*)d_in[4];
  const float* as1 = (const float*)d_in[5];
  const float* ad1 = (const float*)d_in[6];
  const float* b1  = (const float*)d_in[7];
  const float* W2  = (const float*)d_in[8];
  const float* as2 = (const float*)d_in[9];
  const float* ad2 = (const float*)d_in[10];
  const float* b2  = (const float*)d_in[11];
  const float* Wp1 = (const float*)d_in[12];
  const float* bp1 = (const float*)d_in[13];
  const float* Wp2 = (const float*)d_in[14];
  const float* bp2 = (const float*)d_in[15];

  const int N = in_sizes[0] / 8;     // x is [N, 8]
  const int E = in_sizes[1] / 2;     // edge_index is [2, E]
  const int G = out_size;            // output is [G, 1]
  const int Etot = E + N;
  const int* esrc = ei;
  const int* edst = ei + E;

  float* ws = (float*)d_ws;
  size_t o = 0;
  float* hproj = ws + o; o += (size_t)N*HC;
  float* a_s   = ws + o; o += (size_t)N*HEADS;
  float* a_d   = ws + o; o += (size_t)N*HEADS;
  float* den   = ws + o; o += (size_t)N*HEADS;
  float* accum = ws + o; o += (size_t)N*CH;
  float* feat  = ws + o; o += (size_t)N*CH;

  const int eb = (Etot + 255) / 256;          // edge kernels, thread/edge
  const int ab = (Etot + 3) / 4;              // edge_accum, wave/edge, 4 waves/block
  const int nb = (N*CH + 255) / 256;          // node-feature kernels

  // ---------------- layer 1 (Fin = 8) ----------------
  hipMemsetAsync(den,   0, (size_t)N*HEADS*sizeof(float), stream);
  hipMemsetAsync(accum, 0, (size_t)N*CH*sizeof(float), stream);
  proj_kernel<8,8><<<(N+7)/8, 256, 0, stream>>>(x, W1, as1, ad1, hproj, a_s, a_d, N);
  edge_den_kernel<<<eb, 256, 0, stream>>>(esrc, edst, E, N, a_s, a_d, den);
  edge_accum_kernel<<<ab, 256, 0, stream>>>(esrc, edst, E, N, a_s, a_d, den, hproj, accum);
  node_finish_kernel<<<nb, 256, 0, stream>>>(accum, b1, feat, N);

  // ---------------- layer 2 (Fin = 64) ----------------
  hipMemsetAsync(den,   0, (size_t)N*HEADS*sizeof(float), stream);
  hipMemsetAsync(accum, 0, (size_t)N*CH*sizeof(float), stream);
  proj_kernel<64,8><<<(N+7)/8, 256, 0, stream>>>(feat, W2, as2, ad2, hproj, a_s, a_d, N);
  edge_den_kernel<<<eb, 256, 0, stream>>>(esrc, edst, E, N, a_s, a_d, den);
  edge_accum_kernel<<<ab, 256, 0, stream>>>(esrc, edst, E, N, a_s, a_d, den, hproj, accum);

  // ---------------- fused bias/relu + pool + MLP ----------------
  pool_mlp_kernel<<<G, 256, 0, stream>>>(accum, b2, bat, N, Wp1, bp1, Wp2, bp2, (float*)d_out);
}

// Round 3
// 982.891 us; speedup vs baseline: 1.6958x; 1.0360x over previous
//
#include <hip/hip_runtime.h>

#define HEADS 4
#define CH 64
#define HC 256   // HEADS*CH
#define NEG 0.2f

__device__ __forceinline__ unsigned short f2bf(float f){
  unsigned u = __float_as_uint(f);
  u += 0x7fffu + ((u >> 16) & 1u);          // round-to-nearest-even
  return (unsigned short)(u >> 16);
}
__device__ __forceinline__ float bf2f(unsigned short s){
  return __uint_as_float(((unsigned)s) << 16);
}

// h = x @ W ; hproj stored bf16 packed [n][c][h] (ushort4 per (n,c)).
// a_s[n,h] = sum_c h*att_src ; a_d likewise (fp32).
// Block = 256 threads; wave w handles head w (64 channels); NB nodes/block.
template<int FIN, int NB>
__global__ __launch_bounds__(256)
void proj_kernel(const float* __restrict__ x, const float* __restrict__ W,
                 const float* __restrict__ att_src, const float* __restrict__ att_dst,
                 unsigned short* __restrict__ hproj, float* __restrict__ a_s, float* __restrict__ a_d,
                 int N)
{
  __shared__ float xs[NB][FIN];
  const int t = threadIdx.x;
  const int n0 = blockIdx.x * NB;
  for (int i = t; i < NB*FIN; i += 256){
    int n = n0 + i / FIN;
    xs[i/FIN][i%FIN] = (n < N) ? x[(size_t)n*FIN + (i % FIN)] : 0.f;
  }
  __syncthreads();
  const int lane = t & 63;
  const int head = t >> 6;
  const int col  = head*CH + lane;
  float wcol[FIN];
#pragma unroll
  for (int k = 0; k < FIN; ++k) wcol[k] = W[(size_t)k*HC + col];
  const float attS = att_src[col];
  const float attD = att_dst[col];
  for (int i = 0; i < NB; ++i){
    int n = n0 + i;
    if (n >= N) break;
    float acc = 0.f;
#pragma unroll
    for (int k = 0; k < FIN; ++k) acc += xs[i][k] * wcol[k];
    hproj[((size_t)n*CH + lane)*HEADS + head] = f2bf(acc);
    float ps = acc*attS, pd = acc*attD;
#pragma unroll
    for (int off = 32; off; off >>= 1){
      ps += __shfl_down(ps, off);
      pd += __shfl_down(pd, off);
    }
    if (lane == 0){ a_s[n*HEADS + head] = ps; a_d[n*HEADS + head] = pd; }
  }
}

// Edge pass A (thread/edge): ex[e,h] = exp(leaky(a_s[src]+a_d[dst])); den[dst,h] += ex
__global__ __launch_bounds__(256)
void edge_exp_kernel(const int* __restrict__ esrc, const int* __restrict__ edst,
                     int E, int N,
                     const float* __restrict__ a_s, const float* __restrict__ a_d,
                     float* __restrict__ ex, float* __restrict__ den)
{
  int e = blockIdx.x*256 + threadIdx.x;
  int Etot = E + N;
  if (e >= Etot) return;
  int s, d;
  if (e < E){ s = esrc[e]; d = edst[e]; } else { s = d = e - E; }
  const float4 as = *(const float4*)(a_s + (size_t)s*4);
  const float4 ad = *(const float4*)(a_d + (size_t)d*4);
  float ev[4] = {as.x+ad.x, as.y+ad.y, as.z+ad.z, as.w+ad.w};
  float4 exv;
#pragma unroll
  for (int h = 0; h < 4; ++h){
    float v = ev[h] > 0.f ? ev[h] : NEG*ev[h];
    ((float*)&exv)[h] = __expf(v);
  }
  *(float4*)(ex + (size_t)e*4) = exv;
#pragma unroll
  for (int h = 0; h < 4; ++h)
    atomicAdd(den + (size_t)d*4 + h, ((float*)&exv)[h]);
}

// Edge pass B: wave per edge, lane = channel.
// accum[dst,c] += (1/H) * sum_h (ex/den) * hproj_bf16[src,c,h]
__global__ __launch_bounds__(256)
void edge_accum_kernel(const int* __restrict__ esrc, const int* __restrict__ edst,
                       int E, int N,
                       const float* __restrict__ ex, const float* __restrict__ den,
                       const unsigned short* __restrict__ hproj, float* __restrict__ accum)
{
  int wid  = (blockIdx.x*256 + threadIdx.x) >> 6;
  int lane = threadIdx.x & 63;
  int Etot = E + N;
  if (wid >= Etot) return;
  int s, d;
  if (wid < E){ s = esrc[wid]; d = edst[wid]; } else { s = d = wid - E; }
  const float4 exv = *(const float4*)(ex + (size_t)wid*4);
  const float4 dn  = *(const float4*)(den + (size_t)d*4);
  const float a0 = exv.x * __builtin_amdgcn_rcpf(dn.x);
  const float a1 = exv.y * __builtin_amdgcn_rcpf(dn.y);
  const float a2 = exv.z * __builtin_amdgcn_rcpf(dn.z);
  const float a3 = exv.w * __builtin_amdgcn_rcpf(dn.w);
  const ushort4 hv = ((const ushort4*)hproj)[(size_t)s*CH + lane];
  float val = a0*bf2f(hv.x) + a1*bf2f(hv.y) + a2*bf2f(hv.z) + a3*bf2f(hv.w);
  atomicAdd(accum + (size_t)d*CH + lane, 0.25f*val);
}

// feat = relu(accum + bias)   (layer-1 only; layer-2 finish fused into pool_mlp)
__global__ __launch_bounds__(256)
void node_finish_kernel(const float* __restrict__ accum, const float* __restrict__ bias,
                        float* __restrict__ feat, int N)
{
  int i = blockIdx.x*256 + threadIdx.x;
  if (i >= N*CH) return;
  float v = accum[i] + bias[i & 63];
  feat[i] = fmaxf(v, 0.f);
}

// Fused: bias+relu of layer-2 accum -> per-graph mean pool (batch sorted, binary
// search segment bounds; no atomics) -> 64->32->1 MLP. One block per graph.
__global__ __launch_bounds__(256)
void pool_mlp_kernel(const float* __restrict__ accum, const float* __restrict__ bias,
                     const int* __restrict__ batch, int N,
                     const float* __restrict__ Wp1, const float* __restrict__ bp1,
                     const float* __restrict__ Wp2, const float* __restrict__ bp2,
                     float* __restrict__ out)
{
  const int g = blockIdx.x;
  __shared__ int seg[2];
  __shared__ float part[256];
  __shared__ float pooled[CH];
  if (threadIdx.x < 2){
    int target = g + (int)threadIdx.x;
    int lo = 0, hi = N;
    while (lo < hi){ int mid = (lo + hi) >> 1; if (batch[mid] < target) lo = mid + 1; else hi = mid; }
    seg[threadIdx.x] = lo;
  }
  __syncthreads();
  const int start = seg[0], end = seg[1];
  const int c = threadIdx.x & 63, w = threadIdx.x >> 6;
  float acc = 0.f;
  const float bc = bias[c];
  for (int n = start + w; n < end; n += 4)
    acc += fmaxf(accum[(size_t)n*CH + c] + bc, 0.f);
  part[threadIdx.x] = acc;
  __syncthreads();
  if (threadIdx.x < CH){
    float s = part[threadIdx.x] + part[threadIdx.x+64] + part[threadIdx.x+128] + part[threadIdx.x+192];
    pooled[threadIdx.x] = s / fmaxf((float)(end - start), 1.f);
  }
  __syncthreads();
  float hid = 0.f;
  if (threadIdx.x < 32){
    float a2 = bp1[threadIdx.x];
#pragma unroll
    for (int k = 0; k < CH; ++k) a2 += pooled[k] * Wp1[k*32 + threadIdx.x];
    hid = fmaxf(a2, 0.f) * Wp2[threadIdx.x];
  }
#pragma unroll
  for (int off = 16; off; off >>= 1) hid += __shfl_down(hid, off);
  if (threadIdx.x == 0) out[g] = hid + bp2[0];
}

extern "C" void kernel_launch(void* const* d_in, const int* in_sizes, int n_in,
                              void* d_out, int out_size, void* d_ws, size_t ws_size,
                              hipStream_t stream)
{
  const float* x   = (const float*)d_in[0];
  const int*   ei  = (const int*)d_in[1];
  const int*   bat = (const int*)d_in[2];
  const float* W1  = (const float*)d_in[4];
  const float* as1 = (const float*)d_in[5];
  const float* ad1 = (const float*)d_in[6];
  const float* b1  = (const float*)d_in[7];
  const float* W2  = (const float*)d_in[8];
  const float* as2 = (const float*)d_in[9];
  const float* ad2 = (const float*)d_in[10];
  const float* b2  = (const float*)d_in[11];
  const float* Wp1 = (const float*)d_in[12];
  const float* bp1 = (const float*)d_in[13];
  const float* Wp2 = (const float*)d_in[14];
  const float* bp2 = (const float*)d_in[15];

  const int N = in_sizes[0] / 8;     // x is [N, 8]
  const int E = in_sizes[1] / 2;     // edge_index is [2, E]
  const int G = out_size;            // output is [G, 1]
  const int Etot = E + N;
  const int* esrc = ei;
  const int* edst = ei + E;

  char* wsb = (char*)d_ws;
  size_t o = 0;
  auto carve = [&](size_t bytes)->char*{
    char* p = wsb + o; o += (bytes + 255) & ~(size_t)255; return p;
  };
  unsigned short* hproj = (unsigned short*)carve((size_t)N*HC*sizeof(unsigned short));
  float* a_s  = (float*)carve((size_t)N*HEADS*sizeof(float));
  float* a_d  = (float*)carve((size_t)N*HEADS*sizeof(float));
  float* den  = (float*)carve((size_t)N*HEADS*sizeof(float));
  float* ex   = (float*)carve((size_t)Etot*HEADS*sizeof(float));
  float* accum= (float*)carve((size_t)N*CH*sizeof(float));
  float* feat = (float*)carve((size_t)N*CH*sizeof(float));

  const int eb = (Etot + 255) / 256;          // edge kernels, thread/edge
  const int ab = (Etot + 3) / 4;              // edge_accum, wave/edge, 4 waves/block
  const int nb = (N*CH + 255) / 256;          // node-feature kernels

  // ---------------- layer 1 (Fin = 8) ----------------
  hipMemsetAsync(den,   0, (size_t)N*HEADS*sizeof(float), stream);
  hipMemsetAsync(accum, 0, (size_t)N*CH*sizeof(float), stream);
  proj_kernel<8,8><<<(N+7)/8, 256, 0, stream>>>(x, W1, as1, ad1, hproj, a_s, a_d, N);
  edge_exp_kernel<<<eb, 256, 0, stream>>>(esrc, edst, E, N, a_s, a_d, ex, den);
  edge_accum_kernel<<<ab, 256, 0, stream>>>(esrc, edst, E, N, ex, den, hproj, accum);
  node_finish_kernel<<<nb, 256, 0, stream>>>(accum, b1, feat, N);

  // ---------------- layer 2 (Fin = 64) ----------------
  hipMemsetAsync(den,   0, (size_t)N*HEADS*sizeof(float), stream);
  hipMemsetAsync(accum, 0, (size_t)N*CH*sizeof(float), stream);
  proj_kernel<64,8><<<(N+7)/8, 256, 0, stream>>>(feat, W2, as2, ad2, hproj, a_s, a_d, N);
  edge_exp_kernel<<<eb, 256, 0, stream>>>(esrc, edst, E, N, a_s, a_d, ex, den);
  edge_accum_kernel<<<ab, 256, 0, stream>>>(esrc, edst, E, N, ex, den, hproj, accum);

  // ---------------- fused bias/relu + pool + MLP ----------------
  pool_mlp_kernel<<<G, 256, 0, stream>>>(accum, b2, bat, N, Wp1, bp1, Wp2, bp2, (float*)d_out);
}

// Round 4
// 472.485 us; speedup vs baseline: 3.5278x; 2.0803x over previous
//
#include <hip/hip_runtime.h>

#define HEADS 4
#define CH 64
#define HC 256   // HEADS*CH
#define NEG 0.2f

__device__ __forceinline__ unsigned short f2bf(float f){
  unsigned u = __float_as_uint(f);
  u += 0x7fffu + ((u >> 16) & 1u);          // round-to-nearest-even
  return (unsigned short)(u >> 16);
}
__device__ __forceinline__ float bf2f(unsigned short s){
  return __uint_as_float(((unsigned)s) << 16);
}

// ---------------- CSR build (graph identical for both layers) ----------------
__global__ __launch_bounds__(256)
void deg_count_kernel(const int* __restrict__ esrc, const int* __restrict__ edst,
                      int E, int N, int* __restrict__ deg)
{
  int e = blockIdx.x*256 + threadIdx.x;
  if (e >= E + N) return;
  int d = (e < E) ? edst[e] : e - E;
  atomicAdd(deg + d, 1);
}

// per-256-chunk exclusive scan; block sums to bsum
__global__ __launch_bounds__(256)
void scan1_kernel(const int* __restrict__ deg, int* __restrict__ excl,
                  int* __restrict__ bsum, int N)
{
  __shared__ int sm[256];
  int i = blockIdx.x*256 + threadIdx.x;
  int v = (i < N) ? deg[i] : 0;
  sm[threadIdx.x] = v; __syncthreads();
  for (int off = 1; off < 256; off <<= 1){
    int t = (threadIdx.x >= off) ? sm[threadIdx.x - off] : 0;
    __syncthreads();
    sm[threadIdx.x] += t;
    __syncthreads();
  }
  if (i < N) excl[i] = sm[threadIdx.x] - v;
  if (threadIdx.x == 255) bsum[blockIdx.x] = sm[255];
}

// single-block exclusive scan of block sums (nb <= 512)
__global__ __launch_bounds__(512)
void scan2_kernel(int* __restrict__ bsum, int nb)
{
  __shared__ int sm[512];
  int v = (threadIdx.x < nb) ? bsum[threadIdx.x] : 0;
  sm[threadIdx.x] = v; __syncthreads();
  for (int off = 1; off < 512; off <<= 1){
    int t = (threadIdx.x >= off) ? sm[threadIdx.x - off] : 0;
    __syncthreads();
    sm[threadIdx.x] += t;
    __syncthreads();
  }
  if (threadIdx.x < nb) bsum[threadIdx.x] = sm[threadIdx.x] - v;
}

// add block offsets; init cursor
__global__ __launch_bounds__(256)
void scan3_kernel(int* __restrict__ excl, const int* __restrict__ bsum,
                  int* __restrict__ cursor, int N)
{
  int i = blockIdx.x*256 + threadIdx.x;
  if (i >= N) return;
  int r = excl[i] + bsum[blockIdx.x];
  excl[i] = r; cursor[i] = r;
}

__global__ __launch_bounds__(256)
void scatter_kernel(const int* __restrict__ esrc, const int* __restrict__ edst,
                    int E, int N, int* __restrict__ cursor, int* __restrict__ ssrc)
{
  int e = blockIdx.x*256 + threadIdx.x;
  if (e >= E + N) return;
  int s, d;
  if (e < E){ s = esrc[e]; d = edst[e]; } else { s = d = e - E; }
  int pos = atomicAdd(cursor + d, 1);
  ssrc[pos] = s;
}

// ---------------- projection ----------------
// h = x @ W ; hproj stored bf16 packed [n][c][h] (ushort4 per (n,c)).
// a_s[n,h] = sum_c h*att_src ; a_d likewise (fp32).
template<int FIN, int NB>
__global__ __launch_bounds__(256)
void proj_kernel(const float* __restrict__ x, const float* __restrict__ W,
                 const float* __restrict__ att_src, const float* __restrict__ att_dst,
                 unsigned short* __restrict__ hproj, float* __restrict__ a_s, float* __restrict__ a_d,
                 int N)
{
  __shared__ float xs[NB][FIN];
  const int t = threadIdx.x;
  const int n0 = blockIdx.x * NB;
  for (int i = t; i < NB*FIN; i += 256){
    int n = n0 + i / FIN;
    xs[i/FIN][i%FIN] = (n < N) ? x[(size_t)n*FIN + (i % FIN)] : 0.f;
  }
  __syncthreads();
  const int lane = t & 63;
  const int head = t >> 6;
  const int col  = head*CH + lane;
  float wcol[FIN];
#pragma unroll
  for (int k = 0; k < FIN; ++k) wcol[k] = W[(size_t)k*HC + col];
  const float attS = att_src[col];
  const float attD = att_dst[col];
  for (int i = 0; i < NB; ++i){
    int n = n0 + i;
    if (n >= N) break;
    float acc = 0.f;
#pragma unroll
    for (int k = 0; k < FIN; ++k) acc += xs[i][k] * wcol[k];
    hproj[((size_t)n*CH + lane)*HEADS + head] = f2bf(acc);
    float ps = acc*attS, pd = acc*attD;
#pragma unroll
    for (int off = 32; off; off >>= 1){
      ps += __shfl_down(ps, off);
      pd += __shfl_down(pd, off);
    }
    if (lane == 0){ a_s[n*HEADS + head] = ps; a_d[n*HEADS + head] = pd; }
  }
}

// ---------------- fused per-dst aggregation ----------------
// wave per dst node: lanes compute exp(leaky(logit)) for the row's edges in
// parallel, then a broadcast loop gathers hproj[src] (512B coalesced per edge),
// accumulates per-head, softmax-normalizes, head-means, +bias, ReLU, one store.
__global__ __launch_bounds__(256)
void gat_aggregate_kernel(const int* __restrict__ rowstart, const int* __restrict__ ssrc,
                          int N, int Etot,
                          const float* __restrict__ a_s, const float* __restrict__ a_d,
                          const unsigned short* __restrict__ hproj,
                          const float* __restrict__ bias,
                          float* __restrict__ outf)
{
  const int d    = (blockIdx.x*256 + threadIdx.x) >> 6;
  const int lane = threadIdx.x & 63;
  if (d >= N) return;
  const int start = rowstart[d];
  const int end   = (d == N-1) ? Etot : rowstart[d+1];
  const float4 ad4 = *(const float4*)(a_d + (size_t)d*4);
  float acc0=0.f, acc1=0.f, acc2=0.f, acc3=0.f;
  float den0=0.f, den1=0.f, den2=0.f, den3=0.f;
  for (int base = start; base < end; base += 64){
    const int cnt = min(64, end - base);
    float e0=0.f, e1=0.f, e2=0.f, e3=0.f; int sreg = 0;
    if (lane < cnt){
      sreg = ssrc[base + lane];
      const float4 as4 = *(const float4*)(a_s + (size_t)sreg*4);
      float v;
      v = as4.x + ad4.x; v = v > 0.f ? v : NEG*v; e0 = __expf(v);
      v = as4.y + ad4.y; v = v > 0.f ? v : NEG*v; e1 = __expf(v);
      v = as4.z + ad4.z; v = v > 0.f ? v : NEG*v; e2 = __expf(v);
      v = as4.w + ad4.w; v = v > 0.f ? v : NEG*v; e3 = __expf(v);
    }
    for (int k = 0; k < cnt; ++k){
      const int   s  = __shfl(sreg, k);
      const float x0 = __shfl(e0, k), x1 = __shfl(e1, k),
                  x2 = __shfl(e2, k), x3 = __shfl(e3, k);
      const ushort4 hv = ((const ushort4*)hproj)[(size_t)s*CH + lane];
      acc0 += x0*bf2f(hv.x); acc1 += x1*bf2f(hv.y);
      acc2 += x2*bf2f(hv.z); acc3 += x3*bf2f(hv.w);
      den0 += x0; den1 += x1; den2 += x2; den3 += x3;
    }
  }
  float val = 0.25f*(acc0*__builtin_amdgcn_rcpf(den0) + acc1*__builtin_amdgcn_rcpf(den1)
                   + acc2*__builtin_amdgcn_rcpf(den2) + acc3*__builtin_amdgcn_rcpf(den3));
  val = fmaxf(val + bias[lane], 0.f);
  outf[(size_t)d*CH + lane] = val;
}

// ---------------- pool + MLP (feat already bias'd+ReLU'd) ----------------
__global__ __launch_bounds__(256)
void pool_mlp_kernel(const float* __restrict__ feat,
                     const int* __restrict__ batch, int N,
                     const float* __restrict__ Wp1, const float* __restrict__ bp1,
                     const float* __restrict__ Wp2, const float* __restrict__ bp2,
                     float* __restrict__ out)
{
  const int g = blockIdx.x;
  __shared__ int seg[2];
  __shared__ float part[256];
  __shared__ float pooled[CH];
  if (threadIdx.x < 2){
    int target = g + (int)threadIdx.x;
    int lo = 0, hi = N;
    while (lo < hi){ int mid = (lo + hi) >> 1; if (batch[mid] < target) lo = mid + 1; else hi = mid; }
    seg[threadIdx.x] = lo;
  }
  __syncthreads();
  const int start = seg[0], end = seg[1];
  const int c = threadIdx.x & 63, w = threadIdx.x >> 6;
  float acc = 0.f;
  for (int n = start + w; n < end; n += 4)
    acc += feat[(size_t)n*CH + c];
  part[threadIdx.x] = acc;
  __syncthreads();
  if (threadIdx.x < CH){
    float s = part[threadIdx.x] + part[threadIdx.x+64] + part[threadIdx.x+128] + part[threadIdx.x+192];
    pooled[threadIdx.x] = s / fmaxf((float)(end - start), 1.f);
  }
  __syncthreads();
  float hid = 0.f;
  if (threadIdx.x < 32){
    float a2 = bp1[threadIdx.x];
#pragma unroll
    for (int k = 0; k < CH; ++k) a2 += pooled[k] * Wp1[k*32 + threadIdx.x];
    hid = fmaxf(a2, 0.f) * Wp2[threadIdx.x];
  }
#pragma unroll
  for (int off = 16; off; off >>= 1) hid += __shfl_down(hid, off);
  if (threadIdx.x == 0) out[g] = hid + bp2[0];
}

extern "C" void kernel_launch(void* const* d_in, const int* in_sizes, int n_in,
                              void* d_out, int out_size, void* d_ws, size_t ws_size,
                              hipStream_t stream)
{
  const float* x   = (const float*)d_in[0];
  const int*   ei  = (const int*)d_in[1];
  const int*   bat = (const int*)d_in[2];
  const float* W1  = (const float*)d_in[4];
  const float* as1 = (const float*)d_in[5];
  const float* ad1 = (const float*)d_in[6];
  const float* b1  = (const float*)d_in[7];
  const float* W2  = (const float*)d_in[8];
  const float* as2 = (const float*)d_in[9];
  const float* ad2 = (const float*)d_in[10];
  const float* b2  = (const float*)d_in[11];
  const float* Wp1 = (const float*)d_in[12];
  const float* bp1 = (const float*)d_in[13];
  const float* Wp2 = (const float*)d_in[14];
  const float* bp2 = (const float*)d_in[15];

  const int N = in_sizes[0] / 8;     // x is [N, 8]
  const int E = in_sizes[1] / 2;     // edge_index is [2, E]
  const int G = out_size;            // output is [G, 1]
  const int Etot = E + N;
  const int* esrc = ei;
  const int* edst = ei + E;

  char* wsb = (char*)d_ws;
  size_t o = 0;
  auto carve = [&](size_t bytes)->char*{
    char* p = wsb + o; o += (bytes + 255) & ~(size_t)255; return p;
  };
  unsigned short* hproj   = (unsigned short*)carve((size_t)N*HC*sizeof(unsigned short));
  float* a_s      = (float*)carve((size_t)N*HEADS*sizeof(float));
  float* a_d      = (float*)carve((size_t)N*HEADS*sizeof(float));
  float* feat     = (float*)carve((size_t)N*CH*sizeof(float));
  int*   rowstart = (int*)carve((size_t)N*sizeof(int));
  int*   cursor   = (int*)carve((size_t)N*sizeof(int));
  int*   deg      = (int*)carve((size_t)N*sizeof(int));
  int*   bsum     = (int*)carve((size_t)512*sizeof(int));
  int*   ssrc     = (int*)carve((size_t)Etot*sizeof(int));

  const int eb  = (Etot + 255) / 256;   // edge-parallel kernels
  const int nb1 = (N + 255) / 256;      // node-parallel (1 thread/node)
  const int ag  = (N + 3) / 4;          // aggregate: wave/node, 4 waves/block

  // ---- CSR build (once; shared by both layers) ----
  hipMemsetAsync(deg, 0, (size_t)N*sizeof(int), stream);
  deg_count_kernel<<<eb, 256, 0, stream>>>(esrc, edst, E, N, deg);
  scan1_kernel<<<nb1, 256, 0, stream>>>(deg, rowstart, bsum, N);
  scan2_kernel<<<1, 512, 0, stream>>>(bsum, nb1);
  scan3_kernel<<<nb1, 256, 0, stream>>>(rowstart, bsum, cursor, N);
  scatter_kernel<<<eb, 256, 0, stream>>>(esrc, edst, E, N, cursor, ssrc);

  // ---- layer 1 (Fin = 8) ----
  proj_kernel<8,8><<<(N+7)/8, 256, 0, stream>>>(x, W1, as1, ad1, hproj, a_s, a_d, N);
  gat_aggregate_kernel<<<ag, 256, 0, stream>>>(rowstart, ssrc, N, Etot, a_s, a_d, hproj, b1, feat);

  // ---- layer 2 (Fin = 64) ----
  proj_kernel<64,8><<<(N+7)/8, 256, 0, stream>>>(feat, W2, as2, ad2, hproj, a_s, a_d, N);
  gat_aggregate_kernel<<<ag, 256, 0, stream>>>(rowstart, ssrc, N, Etot, a_s, a_d, hproj, b2, feat);

  // ---- pool + MLP ----
  pool_mlp_kernel<<<G, 256, 0, stream>>>(feat, bat, N, Wp1, bp1, Wp2, bp2, (float*)d_out);
}

// Round 5
// 419.185 us; speedup vs baseline: 3.9764x; 1.1272x over previous
//
#include <hip/hip_runtime.h>

#define HEADS 4
#define CH 64
#define HC 256   // HEADS*CH
#define NEG 0.2f

__device__ __forceinline__ unsigned short f2bf(float f){
  unsigned u = __float_as_uint(f);
  u += 0x7fffu + ((u >> 16) & 1u);          // round-to-nearest-even
  return (unsigned short)(u >> 16);
}
__device__ __forceinline__ float bf2f(unsigned short s){
  return __uint_as_float(((unsigned)s) << 16);
}

// ---------------- CSR build (graph identical for both layers) ----------------
__global__ __launch_bounds__(256)
void deg_count_kernel(const int* __restrict__ esrc, const int* __restrict__ edst,
                      int E, int N, int* __restrict__ deg)
{
  int e = blockIdx.x*256 + threadIdx.x;
  if (e >= E + N) return;
  int d = (e < E) ? edst[e] : e - E;
  atomicAdd(deg + d, 1);
}

__global__ __launch_bounds__(256)
void scan1_kernel(const int* __restrict__ deg, int* __restrict__ excl,
                  int* __restrict__ bsum, int N)
{
  __shared__ int sm[256];
  int i = blockIdx.x*256 + threadIdx.x;
  int v = (i < N) ? deg[i] : 0;
  sm[threadIdx.x] = v; __syncthreads();
  for (int off = 1; off < 256; off <<= 1){
    int t = (threadIdx.x >= off) ? sm[threadIdx.x - off] : 0;
    __syncthreads();
    sm[threadIdx.x] += t;
    __syncthreads();
  }
  if (i < N) excl[i] = sm[threadIdx.x] - v;
  if (threadIdx.x == 255) bsum[blockIdx.x] = sm[255];
}

__global__ __launch_bounds__(512)
void scan2_kernel(int* __restrict__ bsum, int nb)
{
  __shared__ int sm[512];
  int v = (threadIdx.x < nb) ? bsum[threadIdx.x] : 0;
  sm[threadIdx.x] = v; __syncthreads();
  for (int off = 1; off < 512; off <<= 1){
    int t = (threadIdx.x >= off) ? sm[threadIdx.x - off] : 0;
    __syncthreads();
    sm[threadIdx.x] += t;
    __syncthreads();
  }
  if (threadIdx.x < nb) bsum[threadIdx.x] = sm[threadIdx.x] - v;
}

__global__ __launch_bounds__(256)
void scan3_kernel(int* __restrict__ excl, const int* __restrict__ bsum,
                  int* __restrict__ cursor, int N)
{
  int i = blockIdx.x*256 + threadIdx.x;
  if (i >= N) return;
  int r = excl[i] + bsum[blockIdx.x];
  excl[i] = r; cursor[i] = r;
}

__global__ __launch_bounds__(256)
void scatter_kernel(const int* __restrict__ esrc, const int* __restrict__ edst,
                    int E, int N, int* __restrict__ cursor, int* __restrict__ ssrc)
{
  int e = blockIdx.x*256 + threadIdx.x;
  if (e >= E + N) return;
  int s, d;
  if (e < E){ s = esrc[e]; d = edst[e]; } else { s = d = e - E; }
  int pos = atomicAdd(cursor + d, 1);
  ssrc[pos] = s;
}

// ---------------- attention-weight folding ----------------
// wfold[f][j], j=0..7: j<4 -> sum_c W[f][h*64+c]*att_src[h][c] (h=j)
//                      j>=4 -> same with att_dst (h=j-4)
// one block, FIN*8 threads
template<int FIN>
__global__ void fold_kernel(const float* __restrict__ W,
                            const float* __restrict__ att_src, const float* __restrict__ att_dst,
                            float* __restrict__ wfold)
{
  int o = threadIdx.x;               // o = f*8 + j
  int f = o >> 3, j = o & 7;
  int h = j & 3;
  const float* att = (j < 4) ? att_src : att_dst;
  float acc = 0.f;
#pragma unroll
  for (int c = 0; c < CH; ++c)
    acc += W[(size_t)f*HC + h*CH + c] * att[h*CH + c];
  wfold[f*8 + j] = acc;
}

// a_s[n,h], a_d[n,h] = x[n,:] @ wfold ; 8 threads per node, 32 nodes/block
template<int FIN>
__global__ __launch_bounds__(256)
void att_kernel(const float* __restrict__ x, const float* __restrict__ wfold,
                float* __restrict__ a_s, float* __restrict__ a_d, int N)
{
  __shared__ float xs[32][FIN];
  __shared__ float wf[FIN*8];
  const int t = threadIdx.x;
  const int n0 = blockIdx.x * 32;
  for (int i = t; i < FIN*8; i += 256) wf[i] = wfold[i];
  for (int i = t; i < 32*FIN; i += 256){
    int n = n0 + i / FIN;
    xs[i/FIN][i%FIN] = (n < N) ? x[(size_t)n*FIN + (i % FIN)] : 0.f;
  }
  __syncthreads();
  const int nn = t >> 3, j = t & 7;
  const int n = n0 + nn;
  if (n >= N) return;
  float acc = 0.f;
#pragma unroll
  for (int f = 0; f < FIN; ++f) acc += xs[nn][f] * wf[f*8 + j];
  if (j < 4) a_s[(size_t)n*4 + j]     = acc;
  else       a_d[(size_t)n*4 + (j-4)] = acc;
}

// ---------------- projection (hproj only, bf16 packed [n][c][h]) ----------------
template<int FIN, int NB>
__global__ __launch_bounds__(256)
void proj_kernel(const float* __restrict__ x, const float* __restrict__ W,
                 unsigned short* __restrict__ hproj, int N)
{
  __shared__ float xs[NB][FIN];
  __shared__ unsigned short hs[NB][HC];   // [c*4+h]
  const int t = threadIdx.x;
  const int n0 = blockIdx.x * NB;
  for (int i = t; i < NB*FIN; i += 256){
    int n = n0 + i / FIN;
    xs[i/FIN][i%FIN] = (n < N) ? x[(size_t)n*FIN + (i % FIN)] : 0.f;
  }
  __syncthreads();
  const int lane = t & 63;
  const int head = t >> 6;
  const int col  = head*CH + lane;
  float wcol[FIN];
#pragma unroll
  for (int k = 0; k < FIN; ++k) wcol[k] = W[(size_t)k*HC + col];
#pragma unroll
  for (int i = 0; i < NB; ++i){
    float acc = 0.f;
#pragma unroll
    for (int k = 0; k < FIN; ++k) acc += xs[i][k] * wcol[k];
    hs[i][lane*4 + head] = f2bf(acc);
  }
  __syncthreads();
  // coalesced ushort4 stores
  for (int i = t; i < NB*CH; i += 256){
    int n = n0 + (i >> 6);
    if (n >= N) break;
    ((ushort4*)hproj)[(size_t)n*CH + (i & 63)] = ((ushort4*)hs[i >> 6])[i & 63];
  }
}

// ---------------- fused per-dst aggregation ----------------
__global__ __launch_bounds__(256)
void gat_aggregate_kernel(const int* __restrict__ rowstart, const int* __restrict__ ssrc,
                          int N, int Etot,
                          const float* __restrict__ a_s, const float* __restrict__ a_d,
                          const unsigned short* __restrict__ hproj,
                          const float* __restrict__ bias,
                          float* __restrict__ outf)
{
  const int d    = (blockIdx.x*256 + threadIdx.x) >> 6;
  const int lane = threadIdx.x & 63;
  if (d >= N) return;
  const int start = rowstart[d];
  const int end   = (d == N-1) ? Etot : rowstart[d+1];
  const float4 ad4 = *(const float4*)(a_d + (size_t)d*4);
  float acc0=0.f, acc1=0.f, acc2=0.f, acc3=0.f;
  float den0=0.f, den1=0.f, den2=0.f, den3=0.f;
  for (int base = start; base < end; base += 64){
    const int cnt = min(64, end - base);
    float e0=0.f, e1=0.f, e2=0.f, e3=0.f; int sreg = 0;
    if (lane < cnt){
      sreg = ssrc[base + lane];
      const float4 as4 = *(const float4*)(a_s + (size_t)sreg*4);
      float v;
      v = as4.x + ad4.x; v = v > 0.f ? v : NEG*v; e0 = __expf(v);
      v = as4.y + ad4.y; v = v > 0.f ? v : NEG*v; e1 = __expf(v);
      v = as4.z + ad4.z; v = v > 0.f ? v : NEG*v; e2 = __expf(v);
      v = as4.w + ad4.w; v = v > 0.f ? v : NEG*v; e3 = __expf(v);
    }
    for (int k = 0; k < cnt; ++k){
      const int   s  = __shfl(sreg, k);
      const float x0 = __shfl(e0, k), x1 = __shfl(e1, k),
                  x2 = __shfl(e2, k), x3 = __shfl(e3, k);
      const ushort4 hv = ((const ushort4*)hproj)[(size_t)s*CH + lane];
      acc0 += x0*bf2f(hv.x); acc1 += x1*bf2f(hv.y);
      acc2 += x2*bf2f(hv.z); acc3 += x3*bf2f(hv.w);
      den0 += x0; den1 += x1; den2 += x2; den3 += x3;
    }
  }
  float val = 0.25f*(acc0*__builtin_amdgcn_rcpf(den0) + acc1*__builtin_amdgcn_rcpf(den1)
                   + acc2*__builtin_amdgcn_rcpf(den2) + acc3*__builtin_amdgcn_rcpf(den3));
  val = fmaxf(val + bias[lane], 0.f);
  outf[(size_t)d*CH + lane] = val;
}

// ---------------- pool + MLP ----------------
__global__ __launch_bounds__(256)
void pool_mlp_kernel(const float* __restrict__ feat,
                     const int* __restrict__ batch, int N,
                     const float* __restrict__ Wp1, const float* __restrict__ bp1,
                     const float* __restrict__ Wp2, const float* __restrict__ bp2,
                     float* __restrict__ out)
{
  const int g = blockIdx.x;
  __shared__ int seg[2];
  __shared__ float part[256];
  __shared__ float pooled[CH];
  if (threadIdx.x < 2){
    int target = g + (int)threadIdx.x;
    int lo = 0, hi = N;
    while (lo < hi){ int mid = (lo + hi) >> 1; if (batch[mid] < target) lo = mid + 1; else hi = mid; }
    seg[threadIdx.x] = lo;
  }
  __syncthreads();
  const int start = seg[0], end = seg[1];
  const int c = threadIdx.x & 63, w = threadIdx.x >> 6;
  float acc = 0.f;
  for (int n = start + w; n < end; n += 4)
    acc += feat[(size_t)n*CH + c];
  part[threadIdx.x] = acc;
  __syncthreads();
  if (threadIdx.x < CH){
    float s = part[threadIdx.x] + part[threadIdx.x+64] + part[threadIdx.x+128] + part[threadIdx.x+192];
    pooled[threadIdx.x] = s / fmaxf((float)(end - start), 1.f);
  }
  __syncthreads();
  float hid = 0.f;
  if (threadIdx.x < 32){
    float a2 = bp1[threadIdx.x];
#pragma unroll
    for (int k = 0; k < CH; ++k) a2 += pooled[k] * Wp1[k*32 + threadIdx.x];
    hid = fmaxf(a2, 0.f) * Wp2[threadIdx.x];
  }
#pragma unroll
  for (int off = 16; off; off >>= 1) hid += __shfl_down(hid, off);
  if (threadIdx.x == 0) out[g] = hid + bp2[0];
}

extern "C" void kernel_launch(void* const* d_in, const int* in_sizes, int n_in,
                              void* d_out, int out_size, void* d_ws, size_t ws_size,
                              hipStream_t stream)
{
  const float* x   = (const float*)d_in[0];
  const int*   ei  = (const int*)d_in[1];
  const int*   bat = (const int*)d_in[2];
  const float* W1  = (const float*)d_in[4];
  const float* as1 = (const float*)d_in[5];
  const float* ad1 = (const float*)d_in[6];
  const float* b1  = (const float*)d_in[7];
  const float* W2  = (const float*)d_in[8];
  const float* as2 = (const float*)d_in[9];
  const float* ad2 = (const float*)d_in[10];
  const float* b2  = (const float*)d_in[11];
  const float* Wp1 = (const float*)d_in[12];
  const float* bp1 = (const float*)d_in[13];
  const float* Wp2 = (const float*)d_in[14];
  const float* bp2 = (const float*)d_in[15];

  const int N = in_sizes[0] / 8;     // x is [N, 8]
  const int E = in_sizes[1] / 2;     // edge_index is [2, E]
  const int G = out_size;            // output is [G, 1]
  const int Etot = E + N;
  const int* esrc = ei;
  const int* edst = ei + E;

  char* wsb = (char*)d_ws;
  size_t o = 0;
  auto carve = [&](size_t bytes)->char*{
    char* p = wsb + o; o += (bytes + 255) & ~(size_t)255; return p;
  };
  unsigned short* hproj   = (unsigned short*)carve((size_t)N*HC*sizeof(unsigned short));
  float* a_s      = (float*)carve((size_t)N*HEADS*sizeof(float));
  float* a_d      = (float*)carve((size_t)N*HEADS*sizeof(float));
  float* feat     = (float*)carve((size_t)N*CH*sizeof(float));
  float* wfold    = (float*)carve((size_t)64*8*sizeof(float));
  int*   rowstart = (int*)carve((size_t)N*sizeof(int));
  int*   cursor   = (int*)carve((size_t)N*sizeof(int));
  int*   deg      = (int*)carve((size_t)N*sizeof(int));
  int*   bsum     = (int*)carve((size_t)512*sizeof(int));
  int*   ssrc     = (int*)carve((size_t)Etot*sizeof(int));

  const int eb  = (Etot + 255) / 256;
  const int nb1 = (N + 255) / 256;
  const int ag  = (N + 3) / 4;
  const int atb = (N + 31) / 32;

  // ---- CSR build (once; shared by both layers) ----
  hipMemsetAsync(deg, 0, (size_t)N*sizeof(int), stream);
  deg_count_kernel<<<eb, 256, 0, stream>>>(esrc, edst, E, N, deg);
  scan1_kernel<<<nb1, 256, 0, stream>>>(deg, rowstart, bsum, N);
  scan2_kernel<<<1, 512, 0, stream>>>(bsum, nb1);
  scan3_kernel<<<nb1, 256, 0, stream>>>(rowstart, bsum, cursor, N);
  scatter_kernel<<<eb, 256, 0, stream>>>(esrc, edst, E, N, cursor, ssrc);

  // ---- layer 1 (Fin = 8) ----
  fold_kernel<8><<<1, 8*8, 0, stream>>>(W1, as1, ad1, wfold);
  att_kernel<8><<<atb, 256, 0, stream>>>(x, wfold, a_s, a_d, N);
  proj_kernel<8,8><<<(N+7)/8, 256, 0, stream>>>(x, W1, hproj, N);
  gat_aggregate_kernel<<<ag, 256, 0, stream>>>(rowstart, ssrc, N, Etot, a_s, a_d, hproj, b1, feat);

  // ---- layer 2 (Fin = 64) ----
  fold_kernel<64><<<1, 64*8, 0, stream>>>(W2, as2, ad2, wfold);
  att_kernel<64><<<atb, 256, 0, stream>>>(feat, wfold, a_s, a_d, N);
  proj_kernel<64,8><<<(N+7)/8, 256, 0, stream>>>(feat, W2, hproj, N);
  gat_aggregate_kernel<<<ag, 256, 0, stream>>>(rowstart, ssrc, N, Etot, a_s, a_d, hproj, b2, feat);

  // ---- pool + MLP ----
  pool_mlp_kernel<<<G, 256, 0, stream>>>(feat, bat, N, Wp1, bp1, Wp2, bp2, (float*)d_out);
}

// Round 6
// 401.863 us; speedup vs baseline: 4.1478x; 1.0431x over previous
//
#include <hip/hip_runtime.h>

#define HEADS 4
#define CH 64
#define HC 256   // HEADS*CH
#define NEG 0.2f

__device__ __forceinline__ unsigned short f2bf(float f){
  unsigned u = __float_as_uint(f);
  u += 0x7fffu + ((u >> 16) & 1u);          // round-to-nearest-even
  return (unsigned short)(u >> 16);
}
__device__ __forceinline__ float bf2f(unsigned short s){
  return __uint_as_float(((unsigned)s) << 16);
}
__device__ __forceinline__ float rlanef(float v, int k){
  return __uint_as_float((unsigned)__builtin_amdgcn_readlane((int)__float_as_uint(v), k));
}

// ---------------- CSR build (graph identical for both layers) ----------------
__global__ __launch_bounds__(256)
void deg_count_kernel(const int* __restrict__ esrc, const int* __restrict__ edst,
                      int E, int N, int* __restrict__ deg)
{
  int e = blockIdx.x*256 + threadIdx.x;
  if (e >= E + N) return;
  int d = (e < E) ? edst[e] : e - E;
  atomicAdd(deg + d, 1);
}

__global__ __launch_bounds__(256)
void scan1_kernel(const int* __restrict__ deg, int* __restrict__ excl,
                  int* __restrict__ bsum, int N)
{
  __shared__ int sm[256];
  int i = blockIdx.x*256 + threadIdx.x;
  int v = (i < N) ? deg[i] : 0;
  sm[threadIdx.x] = v; __syncthreads();
  for (int off = 1; off < 256; off <<= 1){
    int t = (threadIdx.x >= off) ? sm[threadIdx.x - off] : 0;
    __syncthreads();
    sm[threadIdx.x] += t;
    __syncthreads();
  }
  if (i < N) excl[i] = sm[threadIdx.x] - v;
  if (threadIdx.x == 255) bsum[blockIdx.x] = sm[255];
}

__global__ __launch_bounds__(512)
void scan2_kernel(int* __restrict__ bsum, int nb)
{
  __shared__ int sm[512];
  int v = (threadIdx.x < nb) ? bsum[threadIdx.x] : 0;
  sm[threadIdx.x] = v; __syncthreads();
  for (int off = 1; off < 512; off <<= 1){
    int t = (threadIdx.x >= off) ? sm[threadIdx.x - off] : 0;
    __syncthreads();
    sm[threadIdx.x] += t;
    __syncthreads();
  }
  if (threadIdx.x < nb) bsum[threadIdx.x] = sm[threadIdx.x] - v;
}

__global__ __launch_bounds__(256)
void scan3_kernel(int* __restrict__ excl, const int* __restrict__ bsum,
                  int* __restrict__ cursor, int N)
{
  int i = blockIdx.x*256 + threadIdx.x;
  if (i >= N) return;
  int r = excl[i] + bsum[blockIdx.x];
  excl[i] = r; cursor[i] = r;
}

__global__ __launch_bounds__(256)
void scatter_kernel(const int* __restrict__ esrc, const int* __restrict__ edst,
                    int E, int N, int* __restrict__ cursor, int* __restrict__ ssrc)
{
  int e = blockIdx.x*256 + threadIdx.x;
  if (e >= E + N) return;
  int s, d;
  if (e < E){ s = esrc[e]; d = edst[e]; } else { s = d = e - E; }
  int pos = atomicAdd(cursor + d, 1);
  ssrc[pos] = s;
}

// ---------------- attention-weight folding ----------------
template<int FIN>
__global__ void fold_kernel(const float* __restrict__ W,
                            const float* __restrict__ att_src, const float* __restrict__ att_dst,
                            float* __restrict__ wfold)
{
  int o = threadIdx.x;               // o = f*8 + j
  int f = o >> 3, j = o & 7;
  int h = j & 3;
  const float* att = (j < 4) ? att_src : att_dst;
  float acc = 0.f;
#pragma unroll
  for (int c = 0; c < CH; ++c)
    acc += W[(size_t)f*HC + h*CH + c] * att[h*CH + c];
  wfold[f*8 + j] = acc;
}

// a_s[n,h], a_d[n,h] = x[n,:] @ wfold ; 8 threads per node, 32 nodes/block
template<int FIN>
__global__ __launch_bounds__(256)
void att_kernel(const float* __restrict__ x, const float* __restrict__ wfold,
                float* __restrict__ a_s, float* __restrict__ a_d, int N)
{
  __shared__ float xs[32][FIN];
  __shared__ float wf[FIN*8];
  const int t = threadIdx.x;
  const int n0 = blockIdx.x * 32;
  for (int i = t; i < FIN*8; i += 256) wf[i] = wfold[i];
  for (int i = t; i < 32*FIN; i += 256){
    int n = n0 + i / FIN;
    xs[i/FIN][i%FIN] = (n < N) ? x[(size_t)n*FIN + (i % FIN)] : 0.f;
  }
  __syncthreads();
  const int nn = t >> 3, j = t & 7;
  const int n = n0 + nn;
  if (n >= N) return;
  float acc = 0.f;
#pragma unroll
  for (int f = 0; f < FIN; ++f) acc += xs[nn][f] * wf[f*8 + j];
  if (j < 4) a_s[(size_t)n*4 + j]     = acc;
  else       a_d[(size_t)n*4 + (j-4)] = acc;
}

// ---------------- projection (hproj only, bf16 packed [n][c][h]) ----------------
template<int FIN, int NB>
__global__ __launch_bounds__(256, 4)
void proj_kernel(const float* __restrict__ x, const float* __restrict__ W,
                 unsigned short* __restrict__ hproj, int N)
{
  __shared__ float xs[NB][FIN];
  __shared__ unsigned short hs[NB][HC];   // [c*4+h]
  const int t = threadIdx.x;
  const int n0 = blockIdx.x * NB;
  for (int i = t; i < NB*FIN; i += 256){
    int n = n0 + i / FIN;
    xs[i/FIN][i%FIN] = (n < N) ? x[(size_t)n*FIN + (i % FIN)] : 0.f;
  }
  __syncthreads();
  const int lane = t & 63;
  const int head = t >> 6;
  const int col  = head*CH + lane;
  float wcol[FIN];
#pragma unroll
  for (int k = 0; k < FIN; ++k) wcol[k] = W[(size_t)k*HC + col];
#pragma unroll
  for (int i = 0; i < NB; ++i){
    float acc = 0.f;
#pragma unroll
    for (int k4 = 0; k4 < FIN; k4 += 4){
      const float4 xv = *(const float4*)&xs[i][k4];
      acc += xv.x*wcol[k4] + xv.y*wcol[k4+1] + xv.z*wcol[k4+2] + xv.w*wcol[k4+3];
    }
    hs[i][lane*4 + head] = f2bf(acc);
  }
  __syncthreads();
  for (int i = t; i < NB*CH; i += 256){
    int n = n0 + (i >> 6);
    if (n >= N) break;
    ((ushort4*)hproj)[(size_t)n*CH + (i & 63)] = ((ushort4*)hs[i >> 6])[i & 63];
  }
}

// ---------------- fused per-dst aggregation (v2: readlane + 8-deep gather) ----------------
__global__ __launch_bounds__(256)
void gat_aggregate_kernel(const int* __restrict__ rowstart, const int* __restrict__ ssrc,
                          int N, int Etot,
                          const float* __restrict__ a_s, const float* __restrict__ a_d,
                          const unsigned short* __restrict__ hproj,
                          const float* __restrict__ bias,
                          float* __restrict__ outf)
{
  const int d    = (blockIdx.x*256 + threadIdx.x) >> 6;
  const int lane = threadIdx.x & 63;
  if (d >= N) return;
  const int start = rowstart[d];
  const int end   = (d == N-1) ? Etot : rowstart[d+1];
  const float4 ad4 = *(const float4*)(a_d + (size_t)d*4);
  const ushort4* __restrict__ hp4 = (const ushort4*)hproj;
  float acc0=0.f, acc1=0.f, acc2=0.f, acc3=0.f;
  float den0=0.f, den1=0.f, den2=0.f, den3=0.f;
  for (int base = start; base < end; base += 64){
    const int cnt = min(64, end - base);
    float e0=0.f, e1=0.f, e2=0.f, e3=0.f; int sreg = 0;
    if (lane < cnt){
      sreg = ssrc[base + lane];
      const float4 as4 = *(const float4*)(a_s + (size_t)sreg*4);
      float v;
      v = as4.x + ad4.x; v = v > 0.f ? v : NEG*v; e0 = __expf(v);
      v = as4.y + ad4.y; v = v > 0.f ? v : NEG*v; e1 = __expf(v);
      v = as4.z + ad4.z; v = v > 0.f ? v : NEG*v; e2 = __expf(v);
      v = as4.w + ad4.w; v = v > 0.f ? v : NEG*v; e3 = __expf(v);
    }
    int k = 0;
    for (; k + 8 <= cnt; k += 8){
      int sK[8]; ushort4 hv[8];
#pragma unroll
      for (int j = 0; j < 8; ++j) sK[j] = __builtin_amdgcn_readlane(sreg, k + j);
#pragma unroll
      for (int j = 0; j < 8; ++j) hv[j] = hp4[(size_t)sK[j]*CH + lane];
#pragma unroll
      for (int j = 0; j < 8; ++j){
        const float w0 = rlanef(e0, k+j), w1 = rlanef(e1, k+j),
                    w2 = rlanef(e2, k+j), w3 = rlanef(e3, k+j);
        acc0 += w0*bf2f(hv[j].x); acc1 += w1*bf2f(hv[j].y);
        acc2 += w2*bf2f(hv[j].z); acc3 += w3*bf2f(hv[j].w);
        den0 += w0; den1 += w1; den2 += w2; den3 += w3;
      }
    }
    for (; k < cnt; ++k){
      const int s = __builtin_amdgcn_readlane(sreg, k);
      const float w0 = rlanef(e0, k), w1 = rlanef(e1, k),
                  w2 = rlanef(e2, k), w3 = rlanef(e3, k);
      const ushort4 hv = hp4[(size_t)s*CH + lane];
      acc0 += w0*bf2f(hv.x); acc1 += w1*bf2f(hv.y);
      acc2 += w2*bf2f(hv.z); acc3 += w3*bf2f(hv.w);
      den0 += w0; den1 += w1; den2 += w2; den3 += w3;
    }
  }
  float val = 0.25f*(acc0*__builtin_amdgcn_rcpf(den0) + acc1*__builtin_amdgcn_rcpf(den1)
                   + acc2*__builtin_amdgcn_rcpf(den2) + acc3*__builtin_amdgcn_rcpf(den3));
  val = fmaxf(val + bias[lane], 0.f);
  outf[(size_t)d*CH + lane] = val;
}

// ---------------- pool + MLP ----------------
__global__ __launch_bounds__(256)
void pool_mlp_kernel(const float* __restrict__ feat,
                     const int* __restrict__ batch, int N,
                     const float* __restrict__ Wp1, const float* __restrict__ bp1,
                     const float* __restrict__ Wp2, const float* __restrict__ bp2,
                     float* __restrict__ out)
{
  const int g = blockIdx.x;
  __shared__ int seg[2];
  __shared__ float part[256];
  __shared__ float pooled[CH];
  if (threadIdx.x < 2){
    int target = g + (int)threadIdx.x;
    int lo = 0, hi = N;
    while (lo < hi){ int mid = (lo + hi) >> 1; if (batch[mid] < target) lo = mid + 1; else hi = mid; }
    seg[threadIdx.x] = lo;
  }
  __syncthreads();
  const int start = seg[0], end = seg[1];
  const int c = threadIdx.x & 63, w = threadIdx.x >> 6;
  float acc = 0.f;
  for (int n = start + w; n < end; n += 4)
    acc += feat[(size_t)n*CH + c];
  part[threadIdx.x] = acc;
  __syncthreads();
  if (threadIdx.x < CH){
    float s = part[threadIdx.x] + part[threadIdx.x+64] + part[threadIdx.x+128] + part[threadIdx.x+192];
    pooled[threadIdx.x] = s / fmaxf((float)(end - start), 1.f);
  }
  __syncthreads();
  float hid = 0.f;
  if (threadIdx.x < 32){
    float a2 = bp1[threadIdx.x];
#pragma unroll
    for (int k = 0; k < CH; ++k) a2 += pooled[k] * Wp1[k*32 + threadIdx.x];
    hid = fmaxf(a2, 0.f) * Wp2[threadIdx.x];
  }
#pragma unroll
  for (int off = 16; off; off >>= 1) hid += __shfl_down(hid, off);
  if (threadIdx.x == 0) out[g] = hid + bp2[0];
}

extern "C" void kernel_launch(void* const* d_in, const int* in_sizes, int n_in,
                              void* d_out, int out_size, void* d_ws, size_t ws_size,
                              hipStream_t stream)
{
  const float* x   = (const float*)d_in[0];
  const int*   ei  = (const int*)d_in[1];
  const int*   bat = (const int*)d_in[2];
  const float* W1  = (const float*)d_in[4];
  const float* as1 = (const float*)d_in[5];
  const float* ad1 = (const float*)d_in[6];
  const float* b1  = (const float*)d_in[7];
  const float* W2  = (const float*)d_in[8];
  const float* as2 = (const float*)d_in[9];
  const float* ad2 = (const float*)d_in[10];
  const float* b2  = (const float*)d_in[11];
  const float* Wp1 = (const float*)d_in[12];
  const float* bp1 = (const float*)d_in[13];
  const float* Wp2 = (const float*)d_in[14];
  const float* bp2 = (const float*)d_in[15];

  const int N = in_sizes[0] / 8;     // x is [N, 8]
  const int E = in_sizes[1] / 2;     // edge_index is [2, E]
  const int G = out_size;            // output is [G, 1]
  const int Etot = E + N;
  const int* esrc = ei;
  const int* edst = ei + E;

  char* wsb = (char*)d_ws;
  size_t o = 0;
  auto carve = [&](size_t bytes)->char*{
    char* p = wsb + o; o += (bytes + 255) & ~(size_t)255; return p;
  };
  unsigned short* hproj   = (unsigned short*)carve((size_t)N*HC*sizeof(unsigned short));
  float* a_s      = (float*)carve((size_t)N*HEADS*sizeof(float));
  float* a_d      = (float*)carve((size_t)N*HEADS*sizeof(float));
  float* feat     = (float*)carve((size_t)N*CH*sizeof(float));
  float* wfold    = (float*)carve((size_t)64*8*sizeof(float));
  int*   rowstart = (int*)carve((size_t)N*sizeof(int));
  int*   cursor   = (int*)carve((size_t)N*sizeof(int));
  int*   deg      = (int*)carve((size_t)N*sizeof(int));
  int*   bsum     = (int*)carve((size_t)512*sizeof(int));
  int*   ssrc     = (int*)carve((size_t)Etot*sizeof(int));

  const int eb  = (Etot + 255) / 256;
  const int nb1 = (N + 255) / 256;
  const int ag  = (N + 3) / 4;
  const int atb = (N + 31) / 32;

  // ---- CSR build (once; shared by both layers) ----
  hipMemsetAsync(deg, 0, (size_t)N*sizeof(int), stream);
  deg_count_kernel<<<eb, 256, 0, stream>>>(esrc, edst, E, N, deg);
  scan1_kernel<<<nb1, 256, 0, stream>>>(deg, rowstart, bsum, N);
  scan2_kernel<<<1, 512, 0, stream>>>(bsum, nb1);
  scan3_kernel<<<nb1, 256, 0, stream>>>(rowstart, bsum, cursor, N);
  scatter_kernel<<<eb, 256, 0, stream>>>(esrc, edst, E, N, cursor, ssrc);

  // ---- layer 1 (Fin = 8) ----
  fold_kernel<8><<<1, 8*8, 0, stream>>>(W1, as1, ad1, wfold);
  att_kernel<8><<<atb, 256, 0, stream>>>(x, wfold, a_s, a_d, N);
  proj_kernel<8,16><<<(N+15)/16, 256, 0, stream>>>(x, W1, hproj, N);
  gat_aggregate_kernel<<<ag, 256, 0, stream>>>(rowstart, ssrc, N, Etot, a_s, a_d, hproj, b1, feat);

  // ---- layer 2 (Fin = 64) ----
  fold_kernel<64><<<1, 64*8, 0, stream>>>(W2, as2, ad2, wfold);
  att_kernel<64><<<atb, 256, 0, stream>>>(feat, wfold, a_s, a_d, N);
  proj_kernel<64,16><<<(N+15)/16, 256, 0, stream>>>(feat, W2, hproj, N);
  gat_aggregate_kernel<<<ag, 256, 0, stream>>>(rowstart, ssrc, N, Etot, a_s, a_d, hproj, b2, feat);

  // ---- pool + MLP ----
  pool_mlp_kernel<<<G, 256, 0, stream>>>(feat, bat, N, Wp1, bp1, Wp2, bp2, (float*)d_out);
}

// Round 7
// 396.515 us; speedup vs baseline: 4.2037x; 1.0135x over previous
//
#include <hip/hip_runtime.h>

#define HEADS 4
#define CH 64
#define HC 256   // HEADS*CH
#define NEG 0.2f

__device__ __forceinline__ unsigned short f2bf(float f){
  unsigned u = __float_as_uint(f);
  u += 0x7fffu + ((u >> 16) & 1u);          // round-to-nearest-even
  return (unsigned short)(u >> 16);
}
__device__ __forceinline__ float bf2f(unsigned short s){
  return __uint_as_float(((unsigned)s) << 16);
}
__device__ __forceinline__ float rlanef(float v, int k){
  return __uint_as_float((unsigned)__builtin_amdgcn_readlane((int)__float_as_uint(v), k));
}

// ---------------- CSR build (graph identical for both layers) ----------------
__global__ __launch_bounds__(256)
void deg_count_kernel(const int* __restrict__ esrc, const int* __restrict__ edst,
                      int E, int N, int* __restrict__ deg)
{
  int e = blockIdx.x*256 + threadIdx.x;
  if (e >= E + N) return;
  int d = (e < E) ? edst[e] : e - E;
  atomicAdd(deg + d, 1);
}

__global__ __launch_bounds__(256)
void scan1_kernel(const int* __restrict__ deg, int* __restrict__ excl,
                  int* __restrict__ bsum, int N)
{
  __shared__ int sm[256];
  int i = blockIdx.x*256 + threadIdx.x;
  int v = (i < N) ? deg[i] : 0;
  sm[threadIdx.x] = v; __syncthreads();
  for (int off = 1; off < 256; off <<= 1){
    int t = (threadIdx.x >= off) ? sm[threadIdx.x - off] : 0;
    __syncthreads();
    sm[threadIdx.x] += t;
    __syncthreads();
  }
  if (i < N) excl[i] = sm[threadIdx.x] - v;
  if (threadIdx.x == 255) bsum[blockIdx.x] = sm[255];
}

__global__ __launch_bounds__(512)
void scan2_kernel(int* __restrict__ bsum, int nb)
{
  __shared__ int sm[512];
  int v = (threadIdx.x < nb) ? bsum[threadIdx.x] : 0;
  sm[threadIdx.x] = v; __syncthreads();
  for (int off = 1; off < 512; off <<= 1){
    int t = (threadIdx.x >= off) ? sm[threadIdx.x - off] : 0;
    __syncthreads();
    sm[threadIdx.x] += t;
    __syncthreads();
  }
  if (threadIdx.x < nb) bsum[threadIdx.x] = sm[threadIdx.x] - v;
}

__global__ __launch_bounds__(256)
void scan3_kernel(int* __restrict__ excl, const int* __restrict__ bsum,
                  int* __restrict__ cursor, int N)
{
  int i = blockIdx.x*256 + threadIdx.x;
  if (i >= N) return;
  int r = excl[i] + bsum[blockIdx.x];
  excl[i] = r; cursor[i] = r;
}

__global__ __launch_bounds__(256)
void scatter_kernel(const int* __restrict__ esrc, const int* __restrict__ edst,
                    int E, int N, int* __restrict__ cursor, int* __restrict__ ssrc)
{
  int e = blockIdx.x*256 + threadIdx.x;
  if (e >= E + N) return;
  int s, d;
  if (e < E){ s = esrc[e]; d = edst[e]; } else { s = d = e - E; }
  int pos = atomicAdd(cursor + d, 1);
  ssrc[pos] = s;
}

// ---------------- attention-weight folding ----------------
template<int FIN>
__global__ void fold_kernel(const float* __restrict__ W,
                            const float* __restrict__ att_src, const float* __restrict__ att_dst,
                            float* __restrict__ wfold)
{
  int o = threadIdx.x;               // o = f*8 + j
  int f = o >> 3, j = o & 7;
  int h = j & 3;
  const float* att = (j < 4) ? att_src : att_dst;
  float acc = 0.f;
#pragma unroll
  for (int c = 0; c < CH; ++c)
    acc += W[(size_t)f*HC + h*CH + c] * att[h*CH + c];
  wfold[f*8 + j] = acc;
}

// a_s[n,h], a_d[n,h] = x[n,:] @ wfold ; 8 threads per node, 32 nodes/block
template<int FIN>
__global__ __launch_bounds__(256)
void att_kernel(const float* __restrict__ x, const float* __restrict__ wfold,
                float* __restrict__ a_s, float* __restrict__ a_d, int N)
{
  __shared__ float xs[32][FIN];
  __shared__ float wf[FIN*8];
  const int t = threadIdx.x;
  const int n0 = blockIdx.x * 32;
  for (int i = t; i < FIN*8; i += 256) wf[i] = wfold[i];
  for (int i = t; i < 32*FIN; i += 256){
    int n = n0 + i / FIN;
    xs[i/FIN][i%FIN] = (n < N) ? x[(size_t)n*FIN + (i % FIN)] : 0.f;
  }
  __syncthreads();
  const int nn = t >> 3, j = t & 7;
  const int n = n0 + nn;
  if (n >= N) return;
  float acc = 0.f;
#pragma unroll
  for (int f = 0; f < FIN; ++f) acc += xs[nn][f] * wf[f*8 + j];
  if (j < 4) a_s[(size_t)n*4 + j]     = acc;
  else       a_d[(size_t)n*4 + (j-4)] = acc;
}

// ---------------- projection (layer-2 only; hproj bf16 packed [n][c][h]) ----------------
template<int FIN, int NB>
__global__ __launch_bounds__(256, 4)
void proj_kernel(const float* __restrict__ x, const float* __restrict__ W,
                 unsigned short* __restrict__ hproj, int N)
{
  __shared__ float xs[NB][FIN];
  __shared__ unsigned short hs[NB][HC];   // [c*4+h]
  const int t = threadIdx.x;
  const int n0 = blockIdx.x * NB;
  for (int i = t; i < NB*FIN; i += 256){
    int n = n0 + i / FIN;
    xs[i/FIN][i%FIN] = (n < N) ? x[(size_t)n*FIN + (i % FIN)] : 0.f;
  }
  __syncthreads();
  const int lane = t & 63;
  const int head = t >> 6;
  const int col  = head*CH + lane;
  float wcol[FIN];
#pragma unroll
  for (int k = 0; k < FIN; ++k) wcol[k] = W[(size_t)k*HC + col];
#pragma unroll
  for (int i = 0; i < NB; ++i){
    float acc = 0.f;
#pragma unroll
    for (int k4 = 0; k4 < FIN; k4 += 4){
      const float4 xv = *(const float4*)&xs[i][k4];
      acc += xv.x*wcol[k4] + xv.y*wcol[k4+1] + xv.z*wcol[k4+2] + xv.w*wcol[k4+3];
    }
    hs[i][lane*4 + head] = f2bf(acc);
  }
  __syncthreads();
  for (int i = t; i < NB*CH; i += 256){
    int n = n0 + (i >> 6);
    if (n >= N) break;
    ((ushort4*)hproj)[(size_t)n*CH + (i & 63)] = ((ushort4*)hs[i >> 6])[i & 63];
  }
}

// ---------------- layer 1: fused z-aggregation + projection ----------------
// out[d] = relu( 0.25 * sum_h rcp(den_h) * (z_h @ W1_h) + b1 ),
// z_h[f] = sum_e w_h(e) * x[src_e, f]  (commuted aggregation: 32B/edge gather)
// wave per dst node, grid-stride; W1 fragment (32 floats) resident per lane.
__global__ __launch_bounds__(256)
void gat_l1_kernel(const int* __restrict__ rowstart, const int* __restrict__ ssrc,
                   int N, int Etot,
                   const float* __restrict__ a_s, const float* __restrict__ a_d,
                   const float* __restrict__ x, const float* __restrict__ W1,
                   const float* __restrict__ b1,
                   float* __restrict__ feat, int nwaves)
{
  __shared__ int   slds[4][64];
  __shared__ float wlds[4][4][64];
  __shared__ float zlds[4][64];
  const int wv   = threadIdx.x >> 6;
  const int lane = threadIdx.x & 63;
  const int gwid = blockIdx.x*4 + wv;
  // phase-2 lane roles: parity, head, feature
  const int p  = lane >> 5;
  const int hh = (lane >> 3) & 3;
  const int ff = lane & 7;
  // W1 fragment: Wf[h][f] = W1[f*HC + h*CH + lane]  (coalesced, L2-hot, once per wave)
  float Wf[4][8];
#pragma unroll
  for (int h = 0; h < 4; ++h)
#pragma unroll
    for (int f = 0; f < 8; ++f)
      Wf[h][f] = W1[f*HC + h*CH + lane];
  const float bc = b1[lane];

  for (int d = gwid; d < N; d += nwaves){
    const int start = rowstart[d];
    const int end   = (d == N-1) ? Etot : rowstart[d+1];
    const float4 ad4 = *(const float4*)(a_d + (size_t)d*4);
    float zl = 0.f;
    float dn0=0.f, dn1=0.f, dn2=0.f, dn3=0.f;
    for (int base = start; base < end; base += 64){
      const int cnt = min(64, end - base);
      float e0=0.f, e1=0.f, e2=0.f, e3=0.f; int sreg = 0;
      if (lane < cnt){
        sreg = ssrc[base + lane];
        const float4 as4 = *(const float4*)(a_s + (size_t)sreg*4);
        float v;
        v = as4.x + ad4.x; v = v > 0.f ? v : NEG*v; e0 = __expf(v);
        v = as4.y + ad4.y; v = v > 0.f ? v : NEG*v; e1 = __expf(v);
        v = as4.z + ad4.z; v = v > 0.f ? v : NEG*v; e2 = __expf(v);
        v = as4.w + ad4.w; v = v > 0.f ? v : NEG*v; e3 = __expf(v);
      }
      dn0 += e0; dn1 += e1; dn2 += e2; dn3 += e3;
      slds[wv][lane]    = sreg;   // inactive lanes stage (0, w=0): safe padding
      wlds[wv][0][lane] = e0;
      wlds[wv][1][lane] = e1;
      wlds[wv][2][lane] = e2;
      wlds[wv][3][lane] = e3;
      __builtin_amdgcn_wave_barrier();   // wave-private LDS exchange: fence compiler reordering
      const int iters = (cnt + 1) >> 1;
      for (int k2 = 0; k2 < iters; ++k2){
        const int kk = k2*2 + p;         // kk <= cnt (<64); padded slot has w=0
        const int s  = slds[wv][kk];
        const float w = wlds[wv][hh][kk];
        const float xv = x[(size_t)s*8 + ff];
        zl += w * xv;
      }
      __builtin_amdgcn_wave_barrier();
    }
    // reduce den over lanes (butterfly)
#pragma unroll
    for (int off = 1; off < 64; off <<= 1){
      dn0 += __shfl_xor(dn0, off);
      dn1 += __shfl_xor(dn1, off);
      dn2 += __shfl_xor(dn2, off);
      dn3 += __shfl_xor(dn3, off);
    }
    // z transpose via LDS, then per-lane finish: 32 FMAs
    zlds[wv][lane] = zl;
    __builtin_amdgcn_wave_barrier();
    float acc0=0.f, acc1=0.f, acc2=0.f, acc3=0.f;
#pragma unroll
    for (int f = 0; f < 8; ++f){
      const float z0 = zlds[wv][ 0 + f] + zlds[wv][32 + 0 + f];
      const float z1 = zlds[wv][ 8 + f] + zlds[wv][32 + 8 + f];
      const float z2 = zlds[wv][16 + f] + zlds[wv][32 + 16 + f];
      const float z3 = zlds[wv][24 + f] + zlds[wv][32 + 24 + f];
      acc0 += z0*Wf[0][f]; acc1 += z1*Wf[1][f];
      acc2 += z2*Wf[2][f]; acc3 += z3*Wf[3][f];
    }
    __builtin_amdgcn_wave_barrier();
    float val = 0.25f*(acc0*__builtin_amdgcn_rcpf(dn0) + acc1*__builtin_amdgcn_rcpf(dn1)
                     + acc2*__builtin_amdgcn_rcpf(dn2) + acc3*__builtin_amdgcn_rcpf(dn3));
    val = fmaxf(val + bc, 0.f);
    feat[(size_t)d*CH + lane] = val;
  }
}

// ---------------- layer-2 per-dst aggregation (readlane + 8-deep gather) ----------------
__global__ __launch_bounds__(256)
void gat_aggregate_kernel(const int* __restrict__ rowstart, const int* __restrict__ ssrc,
                          int N, int Etot,
                          const float* __restrict__ a_s, const float* __restrict__ a_d,
                          const unsigned short* __restrict__ hproj,
                          const float* __restrict__ bias,
                          float* __restrict__ outf)
{
  const int d    = (blockIdx.x*256 + threadIdx.x) >> 6;
  const int lane = threadIdx.x & 63;
  if (d >= N) return;
  const int start = rowstart[d];
  const int end   = (d == N-1) ? Etot : rowstart[d+1];
  const float4 ad4 = *(const float4*)(a_d + (size_t)d*4);
  const ushort4* __restrict__ hp4 = (const ushort4*)hproj;
  float acc0=0.f, acc1=0.f, acc2=0.f, acc3=0.f;
  float den0=0.f, den1=0.f, den2=0.f, den3=0.f;
  for (int base = start; base < end; base += 64){
    const int cnt = min(64, end - base);
    float e0=0.f, e1=0.f, e2=0.f, e3=0.f; int sreg = 0;
    if (lane < cnt){
      sreg = ssrc[base + lane];
      const float4 as4 = *(const float4*)(a_s + (size_t)sreg*4);
      float v;
      v = as4.x + ad4.x; v = v > 0.f ? v : NEG*v; e0 = __expf(v);
      v = as4.y + ad4.y; v = v > 0.f ? v : NEG*v; e1 = __expf(v);
      v = as4.z + ad4.z; v = v > 0.f ? v : NEG*v; e2 = __expf(v);
      v = as4.w + ad4.w; v = v > 0.f ? v : NEG*v; e3 = __expf(v);
    }
    int k = 0;
    for (; k + 8 <= cnt; k += 8){
      int sK[8]; ushort4 hv[8];
#pragma unroll
      for (int j = 0; j < 8; ++j) sK[j] = __builtin_amdgcn_readlane(sreg, k + j);
#pragma unroll
      for (int j = 0; j < 8; ++j) hv[j] = hp4[(size_t)sK[j]*CH + lane];
#pragma unroll
      for (int j = 0; j < 8; ++j){
        const float w0 = rlanef(e0, k+j), w1 = rlanef(e1, k+j),
                    w2 = rlanef(e2, k+j), w3 = rlanef(e3, k+j);
        acc0 += w0*bf2f(hv[j].x); acc1 += w1*bf2f(hv[j].y);
        acc2 += w2*bf2f(hv[j].z); acc3 += w3*bf2f(hv[j].w);
        den0 += w0; den1 += w1; den2 += w2; den3 += w3;
      }
    }
    for (; k < cnt; ++k){
      const int s = __builtin_amdgcn_readlane(sreg, k);
      const float w0 = rlanef(e0, k), w1 = rlanef(e1, k),
                  w2 = rlanef(e2, k), w3 = rlanef(e3, k);
      const ushort4 hv = hp4[(size_t)s*CH + lane];
      acc0 += w0*bf2f(hv.x); acc1 += w1*bf2f(hv.y);
      acc2 += w2*bf2f(hv.z); acc3 += w3*bf2f(hv.w);
      den0 += w0; den1 += w1; den2 += w2; den3 += w3;
    }
  }
  float val = 0.25f*(acc0*__builtin_amdgcn_rcpf(den0) + acc1*__builtin_amdgcn_rcpf(den1)
                   + acc2*__builtin_amdgcn_rcpf(den2) + acc3*__builtin_amdgcn_rcpf(den3));
  val = fmaxf(val + bias[lane], 0.f);
  outf[(size_t)d*CH + lane] = val;
}

// ---------------- pool + MLP ----------------
__global__ __launch_bounds__(256)
void pool_mlp_kernel(const float* __restrict__ feat,
                     const int* __restrict__ batch, int N,
                     const float* __restrict__ Wp1, const float* __restrict__ bp1,
                     const float* __restrict__ Wp2, const float* __restrict__ bp2,
                     float* __restrict__ out)
{
  const int g = blockIdx.x;
  __shared__ int seg[2];
  __shared__ float part[256];
  __shared__ float pooled[CH];
  if (threadIdx.x < 2){
    int target = g + (int)threadIdx.x;
    int lo = 0, hi = N;
    while (lo < hi){ int mid = (lo + hi) >> 1; if (batch[mid] < target) lo = mid + 1; else hi = mid; }
    seg[threadIdx.x] = lo;
  }
  __syncthreads();
  const int start = seg[0], end = seg[1];
  const int c = threadIdx.x & 63, w = threadIdx.x >> 6;
  float acc = 0.f;
  for (int n = start + w; n < end; n += 4)
    acc += feat[(size_t)n*CH + c];
  part[threadIdx.x] = acc;
  __syncthreads();
  if (threadIdx.x < CH){
    float s = part[threadIdx.x] + part[threadIdx.x+64] + part[threadIdx.x+128] + part[threadIdx.x+192];
    pooled[threadIdx.x] = s / fmaxf((float)(end - start), 1.f);
  }
  __syncthreads();
  float hid = 0.f;
  if (threadIdx.x < 32){
    float a2 = bp1[threadIdx.x];
#pragma unroll
    for (int k = 0; k < CH; ++k) a2 += pooled[k] * Wp1[k*32 + threadIdx.x];
    hid = fmaxf(a2, 0.f) * Wp2[threadIdx.x];
  }
#pragma unroll
  for (int off = 16; off; off >>= 1) hid += __shfl_down(hid, off);
  if (threadIdx.x == 0) out[g] = hid + bp2[0];
}

extern "C" void kernel_launch(void* const* d_in, const int* in_sizes, int n_in,
                              void* d_out, int out_size, void* d_ws, size_t ws_size,
                              hipStream_t stream)
{
  const float* x   = (const float*)d_in[0];
  const int*   ei  = (const int*)d_in[1];
  const int*   bat = (const int*)d_in[2];
  const float* W1  = (const float*)d_in[4];
  const float* as1 = (const float*)d_in[5];
  const float* ad1 = (const float*)d_in[6];
  const float* b1  = (const float*)d_in[7];
  const float* W2  = (const float*)d_in[8];
  const float* as2 = (const float*)d_in[9];
  const float* ad2 = (const float*)d_in[10];
  const float* b2  = (const float*)d_in[11];
  const float* Wp1 = (const float*)d_in[12];
  const float* bp1 = (const float*)d_in[13];
  const float* Wp2 = (const float*)d_in[14];
  const float* bp2 = (const float*)d_in[15];

  const int N = in_sizes[0] / 8;     // x is [N, 8]
  const int E = in_sizes[1] / 2;     // edge_index is [2, E]
  const int G = out_size;            // output is [G, 1]
  const int Etot = E + N;
  const int* esrc = ei;
  const int* edst = ei + E;

  char* wsb = (char*)d_ws;
  size_t o = 0;
  auto carve = [&](size_t bytes)->char*{
    char* p = wsb + o; o += (bytes + 255) & ~(size_t)255; return p;
  };
  unsigned short* hproj   = (unsigned short*)carve((size_t)N*HC*sizeof(unsigned short));
  float* a_s      = (float*)carve((size_t)N*HEADS*sizeof(float));
  float* a_d      = (float*)carve((size_t)N*HEADS*sizeof(float));
  float* feat     = (float*)carve((size_t)N*CH*sizeof(float));
  float* wfold    = (float*)carve((size_t)64*8*sizeof(float));
  int*   rowstart = (int*)carve((size_t)N*sizeof(int));
  int*   cursor   = (int*)carve((size_t)N*sizeof(int));
  int*   deg      = (int*)carve((size_t)N*sizeof(int));
  int*   bsum     = (int*)carve((size_t)512*sizeof(int));
  int*   ssrc     = (int*)carve((size_t)Etot*sizeof(int));

  const int eb  = (Etot + 255) / 256;
  const int nb1 = (N + 255) / 256;
  const int ag  = (N + 3) / 4;
  const int atb = (N + 31) / 32;
  const int l1b = 2048;                 // gat_l1: persistent-ish waves
  const int l1w = l1b * 4;

  // ---- CSR build (once; shared by both layers) ----
  hipMemsetAsync(deg, 0, (size_t)N*sizeof(int), stream);
  deg_count_kernel<<<eb, 256, 0, stream>>>(esrc, edst, E, N, deg);
  scan1_kernel<<<nb1, 256, 0, stream>>>(deg, rowstart, bsum, N);
  scan2_kernel<<<1, 512, 0, stream>>>(bsum, nb1);
  scan3_kernel<<<nb1, 256, 0, stream>>>(rowstart, bsum, cursor, N);
  scatter_kernel<<<eb, 256, 0, stream>>>(esrc, edst, E, N, cursor, ssrc);

  // ---- layer 1 (Fin = 8): commuted aggregation, fully fused ----
  fold_kernel<8><<<1, 8*8, 0, stream>>>(W1, as1, ad1, wfold);
  att_kernel<8><<<atb, 256, 0, stream>>>(x, wfold, a_s, a_d, N);
  gat_l1_kernel<<<l1b, 256, 0, stream>>>(rowstart, ssrc, N, Etot, a_s, a_d, x, W1, b1, feat, l1w);

  // ---- layer 2 (Fin = 64) ----
  fold_kernel<64><<<1, 64*8, 0, stream>>>(W2, as2, ad2, wfold);
  att_kernel<64><<<atb, 256, 0, stream>>>(feat, wfold, a_s, a_d, N);
  proj_kernel<64,16><<<(N+15)/16, 256, 0, stream>>>(feat, W2, hproj, N);
  gat_aggregate_kernel<<<ag, 256, 0, stream>>>(rowstart, ssrc, N, Etot, a_s, a_d, hproj, b2, feat);

  // ---- pool + MLP ----
  pool_mlp_kernel<<<G, 256, 0, stream>>>(feat, bat, N, Wp1, bp1, Wp2, bp2, (float*)d_out);
}

// Round 8
// 374.712 us; speedup vs baseline: 4.4483x; 1.0582x over previous
//
#include <hip/hip_runtime.h>

#define HEADS 4
#define CH 64
#define HC 256   // HEADS*CH
#define NEG 0.2f

__device__ __forceinline__ unsigned short f2bf(float f){
  unsigned u = __float_as_uint(f);
  u += 0x7fffu + ((u >> 16) & 1u);          // round-to-nearest-even
  return (unsigned short)(u >> 16);
}
__device__ __forceinline__ float bf2f(unsigned short s){
  return __uint_as_float(((unsigned)s) << 16);
}
__device__ __forceinline__ float rlanef(float v, int k){
  return __uint_as_float((unsigned)__builtin_amdgcn_readlane((int)__float_as_uint(v), k));
}

// ---------------- CSR build (graph identical for both layers) ----------------
__global__ __launch_bounds__(256)
void deg_count_kernel(const int* __restrict__ esrc, const int* __restrict__ edst,
                      int E, int N, int* __restrict__ deg)
{
  int e = blockIdx.x*256 + threadIdx.x;
  if (e >= E + N) return;
  int d = (e < E) ? edst[e] : e - E;
  atomicAdd(deg + d, 1);
}

__global__ __launch_bounds__(256)
void scan1_kernel(const int* __restrict__ deg, int* __restrict__ excl,
                  int* __restrict__ bsum, int N)
{
  __shared__ int sm[256];
  int i = blockIdx.x*256 + threadIdx.x;
  int v = (i < N) ? deg[i] : 0;
  sm[threadIdx.x] = v; __syncthreads();
  for (int off = 1; off < 256; off <<= 1){
    int t = (threadIdx.x >= off) ? sm[threadIdx.x - off] : 0;
    __syncthreads();
    sm[threadIdx.x] += t;
    __syncthreads();
  }
  if (i < N) excl[i] = sm[threadIdx.x] - v;
  if (threadIdx.x == 255) bsum[blockIdx.x] = sm[255];
}

__global__ __launch_bounds__(512)
void scan2_kernel(int* __restrict__ bsum, int nb)
{
  __shared__ int sm[512];
  int v = (threadIdx.x < nb) ? bsum[threadIdx.x] : 0;
  sm[threadIdx.x] = v; __syncthreads();
  for (int off = 1; off < 512; off <<= 1){
    int t = (threadIdx.x >= off) ? sm[threadIdx.x - off] : 0;
    __syncthreads();
    sm[threadIdx.x] += t;
    __syncthreads();
  }
  if (threadIdx.x < nb) bsum[threadIdx.x] = sm[threadIdx.x] - v;
}

__global__ __launch_bounds__(256)
void scan3_kernel(int* __restrict__ excl, const int* __restrict__ bsum,
                  int* __restrict__ cursor, int N)
{
  int i = blockIdx.x*256 + threadIdx.x;
  if (i >= N) return;
  int r = excl[i] + bsum[blockIdx.x];
  excl[i] = r; cursor[i] = r;
}

__global__ __launch_bounds__(256)
void scatter_kernel(const int* __restrict__ esrc, const int* __restrict__ edst,
                    int E, int N, int* __restrict__ cursor, int* __restrict__ ssrc)
{
  int e = blockIdx.x*256 + threadIdx.x;
  if (e >= E + N) return;
  int s, d;
  if (e < E){ s = esrc[e]; d = edst[e]; } else { s = d = e - E; }
  int pos = atomicAdd(cursor + d, 1);
  ssrc[pos] = s;
}

// ---------------- attention-weight folding ----------------
template<int FIN>
__global__ void fold_kernel(const float* __restrict__ W,
                            const float* __restrict__ att_src, const float* __restrict__ att_dst,
                            float* __restrict__ wfold)
{
  int o = threadIdx.x;               // o = f*8 + j
  int f = o >> 3, j = o & 7;
  int h = j & 3;
  const float* att = (j < 4) ? att_src : att_dst;
  float acc = 0.f;
#pragma unroll
  for (int c = 0; c < CH; ++c)
    acc += W[(size_t)f*HC + h*CH + c] * att[h*CH + c];
  wfold[f*8 + j] = acc;
}

// a_s[n,h], a_d[n,h] = x[n,:] @ wfold ; 8 threads per node, 32 nodes/block
template<int FIN>
__global__ __launch_bounds__(256)
void att_kernel(const float* __restrict__ x, const float* __restrict__ wfold,
                float* __restrict__ a_s, float* __restrict__ a_d, int N)
{
  __shared__ float xs[32][FIN];
  __shared__ float wf[FIN*8];
  const int t = threadIdx.x;
  const int n0 = blockIdx.x * 32;
  for (int i = t; i < FIN*8; i += 256) wf[i] = wfold[i];
  for (int i = t; i < 32*FIN; i += 256){
    int n = n0 + i / FIN;
    xs[i/FIN][i%FIN] = (n < N) ? x[(size_t)n*FIN + (i % FIN)] : 0.f;
  }
  __syncthreads();
  const int nn = t >> 3, j = t & 7;
  const int n = n0 + nn;
  if (n >= N) return;
  float acc = 0.f;
#pragma unroll
  for (int f = 0; f < FIN; ++f) acc += xs[nn][f] * wf[f*8 + j];
  if (j < 4) a_s[(size_t)n*4 + j]     = acc;
  else       a_d[(size_t)n*4 + (j-4)] = acc;
}

// ---------------- projection (layer-2 only; hproj bf16 packed [n][c][h]) ----------------
template<int FIN, int NB>
__global__ __launch_bounds__(256, 4)
void proj_kernel(const float* __restrict__ x, const float* __restrict__ W,
                 unsigned short* __restrict__ hproj, int N)
{
  __shared__ float xs[NB][FIN];
  __shared__ unsigned short hs[NB][HC];   // [c*4+h]
  const int t = threadIdx.x;
  const int n0 = blockIdx.x * NB;
  for (int i = t; i < NB*FIN; i += 256){
    int n = n0 + i / FIN;
    xs[i/FIN][i%FIN] = (n < N) ? x[(size_t)n*FIN + (i % FIN)] : 0.f;
  }
  __syncthreads();
  const int lane = t & 63;
  const int head = t >> 6;
  const int col  = head*CH + lane;
  float wcol[FIN];
#pragma unroll
  for (int k = 0; k < FIN; ++k) wcol[k] = W[(size_t)k*HC + col];
#pragma unroll
  for (int i = 0; i < NB; ++i){
    float acc = 0.f;
#pragma unroll
    for (int k4 = 0; k4 < FIN; k4 += 4){
      const float4 xv = *(const float4*)&xs[i][k4];
      acc += xv.x*wcol[k4] + xv.y*wcol[k4+1] + xv.z*wcol[k4+2] + xv.w*wcol[k4+3];
    }
    hs[i][lane*4 + head] = f2bf(acc);
  }
  __syncthreads();
  for (int i = t; i < NB*CH; i += 256){
    int n = n0 + (i >> 6);
    if (n >= N) break;
    ((ushort4*)hproj)[(size_t)n*CH + (i & 63)] = ((ushort4*)hs[i >> 6])[i & 63];
  }
}

// ---------------- layer 1: fused z-aggregation + projection (v2) ----------------
// out[d] = relu( 0.25 * sum_h rcp(den_h) * (z_h @ W1_h) + b1 ),
// z_h[f] = sum_e w_h(e) * x[src_e, f]  (commuted aggregation: 32B/edge gather)
// wave per dst node; phase 2: 8 edges/iter, lane=(j,ff), conflict-free float4 LDS.
__global__ __launch_bounds__(256)
void gat_l1_kernel(const int* __restrict__ rowstart, const int* __restrict__ ssrc,
                   int N, int Etot,
                   const float* __restrict__ a_s, const float* __restrict__ a_d,
                   const float* __restrict__ x, const float* __restrict__ W1,
                   const float* __restrict__ b1,
                   float* __restrict__ feat, int nwaves)
{
  __shared__ int    slds[4][64];
  __shared__ float4 wlds[4][64];
  __shared__ float  zlds[4][32];
  const int wv   = threadIdx.x >> 6;
  const int lane = threadIdx.x & 63;
  const int gwid = blockIdx.x*4 + wv;
  const int jj = lane >> 3;      // edge sub-index within 8-edge group
  const int ff = lane & 7;       // feature index
  // W1 fragment: Wf[h][f] = W1[f*HC + h*CH + lane]  (coalesced, L2-hot, once per wave)
  float Wf[4][8];
#pragma unroll
  for (int h = 0; h < 4; ++h)
#pragma unroll
    for (int f = 0; f < 8; ++f)
      Wf[h][f] = W1[f*HC + h*CH + lane];
  const float bc = b1[lane];

  for (int d = gwid; d < N; d += nwaves){
    const int start = rowstart[d];
    const int end   = (d == N-1) ? Etot : rowstart[d+1];
    const float4 ad4 = *(const float4*)(a_d + (size_t)d*4);
    float zl0=0.f, zl1=0.f, zl2=0.f, zl3=0.f;
    float dn0=0.f, dn1=0.f, dn2=0.f, dn3=0.f;
    for (int base = start; base < end; base += 64){
      const int cnt = min(64, end - base);
      float e0=0.f, e1=0.f, e2=0.f, e3=0.f; int sreg = 0;
      if (lane < cnt){
        sreg = ssrc[base + lane];
        const float4 as4 = *(const float4*)(a_s + (size_t)sreg*4);
        float v;
        v = as4.x + ad4.x; v = v > 0.f ? v : NEG*v; e0 = __expf(v);
        v = as4.y + ad4.y; v = v > 0.f ? v : NEG*v; e1 = __expf(v);
        v = as4.z + ad4.z; v = v > 0.f ? v : NEG*v; e2 = __expf(v);
        v = as4.w + ad4.w; v = v > 0.f ? v : NEG*v; e3 = __expf(v);
      }
      dn0 += e0; dn1 += e1; dn2 += e2; dn3 += e3;
      slds[wv][lane] = sreg;                     // padded slots: s=0, w=0 -> contribute 0
      wlds[wv][lane] = make_float4(e0, e1, e2, e3);
      __builtin_amdgcn_wave_barrier();
      const int it8 = (cnt + 7) >> 3;
      for (int t = 0; t < it8; ++t){
        const int k = t*8 + jj;
        const int    s  = slds[wv][k];           // 8 distinct dwords -> conflict-free bcast
        const float4 w4 = wlds[wv][k];           // 8 x b128 = 128B contig -> all 32 banks once
        const float  xv = x[(size_t)s*8 + ff];   // 8x 32B segments, coalesced
        zl0 += w4.x*xv; zl1 += w4.y*xv; zl2 += w4.z*xv; zl3 += w4.w*xv;
      }
      __builtin_amdgcn_wave_barrier();
    }
    // reduce den over all 64 lanes (butterfly)
#pragma unroll
    for (int off = 1; off < 64; off <<= 1){
      dn0 += __shfl_xor(dn0, off);
      dn1 += __shfl_xor(dn1, off);
      dn2 += __shfl_xor(dn2, off);
      dn3 += __shfl_xor(dn3, off);
    }
    // reduce z over the 8 j-groups
#pragma unroll
    for (int off = 8; off < 64; off <<= 1){
      zl0 += __shfl_xor(zl0, off);
      zl1 += __shfl_xor(zl1, off);
      zl2 += __shfl_xor(zl2, off);
      zl3 += __shfl_xor(zl3, off);
    }
    // stage z[h][f] (32 values) to LDS: lanes jj<4 write consecutive dwords
    const float zsel = (jj == 0) ? zl0 : (jj == 1) ? zl1 : (jj == 2) ? zl2 : zl3;
    if (jj < 4) zlds[wv][jj*8 + ff] = zsel;
    __builtin_amdgcn_wave_barrier();
    float acc0=0.f, acc1=0.f, acc2=0.f, acc3=0.f;
#pragma unroll
    for (int f = 0; f < 8; ++f){
      acc0 += zlds[wv][ 0 + f]*Wf[0][f];
      acc1 += zlds[wv][ 8 + f]*Wf[1][f];
      acc2 += zlds[wv][16 + f]*Wf[2][f];
      acc3 += zlds[wv][24 + f]*Wf[3][f];
    }
    __builtin_amdgcn_wave_barrier();
    float val = 0.25f*(acc0*__builtin_amdgcn_rcpf(dn0) + acc1*__builtin_amdgcn_rcpf(dn1)
                     + acc2*__builtin_amdgcn_rcpf(dn2) + acc3*__builtin_amdgcn_rcpf(dn3));
    val = fmaxf(val + bc, 0.f);
    feat[(size_t)d*CH + lane] = val;
  }
}

// ---------------- layer-2 per-dst aggregation (readlane + 8-deep gather) ----------------
__global__ __launch_bounds__(256)
void gat_aggregate_kernel(const int* __restrict__ rowstart, const int* __restrict__ ssrc,
                          int N, int Etot,
                          const float* __restrict__ a_s, const float* __restrict__ a_d,
                          const unsigned short* __restrict__ hproj,
                          const float* __restrict__ bias,
                          float* __restrict__ outf)
{
  const int d    = (blockIdx.x*256 + threadIdx.x) >> 6;
  const int lane = threadIdx.x & 63;
  if (d >= N) return;
  const int start = rowstart[d];
  const int end   = (d == N-1) ? Etot : rowstart[d+1];
  const float4 ad4 = *(const float4*)(a_d + (size_t)d*4);
  const ushort4* __restrict__ hp4 = (const ushort4*)hproj;
  float acc0=0.f, acc1=0.f, acc2=0.f, acc3=0.f;
  float den0=0.f, den1=0.f, den2=0.f, den3=0.f;
  for (int base = start; base < end; base += 64){
    const int cnt = min(64, end - base);
    float e0=0.f, e1=0.f, e2=0.f, e3=0.f; int sreg = 0;
    if (lane < cnt){
      sreg = ssrc[base + lane];
      const float4 as4 = *(const float4*)(a_s + (size_t)sreg*4);
      float v;
      v = as4.x + ad4.x; v = v > 0.f ? v : NEG*v; e0 = __expf(v);
      v = as4.y + ad4.y; v = v > 0.f ? v : NEG*v; e1 = __expf(v);
      v = as4.z + ad4.z; v = v > 0.f ? v : NEG*v; e2 = __expf(v);
      v = as4.w + ad4.w; v = v > 0.f ? v : NEG*v; e3 = __expf(v);
    }
    int k = 0;
    for (; k + 8 <= cnt; k += 8){
      int sK[8]; ushort4 hv[8];
#pragma unroll
      for (int j = 0; j < 8; ++j) sK[j] = __builtin_amdgcn_readlane(sreg, k + j);
#pragma unroll
      for (int j = 0; j < 8; ++j) hv[j] = hp4[(size_t)sK[j]*CH + lane];
#pragma unroll
      for (int j = 0; j < 8; ++j){
        const float w0 = rlanef(e0, k+j), w1 = rlanef(e1, k+j),
                    w2 = rlanef(e2, k+j), w3 = rlanef(e3, k+j);
        acc0 += w0*bf2f(hv[j].x); acc1 += w1*bf2f(hv[j].y);
        acc2 += w2*bf2f(hv[j].z); acc3 += w3*bf2f(hv[j].w);
        den0 += w0; den1 += w1; den2 += w2; den3 += w3;
      }
    }
    for (; k < cnt; ++k){
      const int s = __builtin_amdgcn_readlane(sreg, k);
      const float w0 = rlanef(e0, k), w1 = rlanef(e1, k),
                  w2 = rlanef(e2, k), w3 = rlanef(e3, k);
      const ushort4 hv = hp4[(size_t)s*CH + lane];
      acc0 += w0*bf2f(hv.x); acc1 += w1*bf2f(hv.y);
      acc2 += w2*bf2f(hv.z); acc3 += w3*bf2f(hv.w);
      den0 += w0; den1 += w1; den2 += w2; den3 += w3;
    }
  }
  float val = 0.25f*(acc0*__builtin_amdgcn_rcpf(den0) + acc1*__builtin_amdgcn_rcpf(den1)
                   + acc2*__builtin_amdgcn_rcpf(den2) + acc3*__builtin_amdgcn_rcpf(den3));
  val = fmaxf(val + bias[lane], 0.f);
  outf[(size_t)d*CH + lane] = val;
}

// ---------------- pool + MLP ----------------
__global__ __launch_bounds__(256)
void pool_mlp_kernel(const float* __restrict__ feat,
                     const int* __restrict__ batch, int N,
                     const float* __restrict__ Wp1, const float* __restrict__ bp1,
                     const float* __restrict__ Wp2, const float* __restrict__ bp2,
                     float* __restrict__ out)
{
  const int g = blockIdx.x;
  __shared__ int seg[2];
  __shared__ float part[256];
  __shared__ float pooled[CH];
  if (threadIdx.x < 2){
    int target = g + (int)threadIdx.x;
    int lo = 0, hi = N;
    while (lo < hi){ int mid = (lo + hi) >> 1; if (batch[mid] < target) lo = mid + 1; else hi = mid; }
    seg[threadIdx.x] = lo;
  }
  __syncthreads();
  const int start = seg[0], end = seg[1];
  const int c = threadIdx.x & 63, w = threadIdx.x >> 6;
  float acc = 0.f;
  for (int n = start + w; n < end; n += 4)
    acc += feat[(size_t)n*CH + c];
  part[threadIdx.x] = acc;
  __syncthreads();
  if (threadIdx.x < CH){
    float s = part[threadIdx.x] + part[threadIdx.x+64] + part[threadIdx.x+128] + part[threadIdx.x+192];
    pooled[threadIdx.x] = s / fmaxf((float)(end - start), 1.f);
  }
  __syncthreads();
  float hid = 0.f;
  if (threadIdx.x < 32){
    float a2 = bp1[threadIdx.x];
#pragma unroll
    for (int k = 0; k < CH; ++k) a2 += pooled[k] * Wp1[k*32 + threadIdx.x];
    hid = fmaxf(a2, 0.f) * Wp2[threadIdx.x];
  }
#pragma unroll
  for (int off = 16; off; off >>= 1) hid += __shfl_down(hid, off);
  if (threadIdx.x == 0) out[g] = hid + bp2[0];
}

extern "C" void kernel_launch(void* const* d_in, const int* in_sizes, int n_in,
                              void* d_out, int out_size, void* d_ws, size_t ws_size,
                              hipStream_t stream)
{
  const float* x   = (const float*)d_in[0];
  const int*   ei  = (const int*)d_in[1];
  const int*   bat = (const int*)d_in[2];
  const float* W1  = (const float*)d_in[4];
  const float* as1 = (const float*)d_in[5];
  const float* ad1 = (const float*)d_in[6];
  const float* b1  = (const float*)d_in[7];
  const float* W2  = (const float*)d_in[8];
  const float* as2 = (const float*)d_in[9];
  const float* ad2 = (const float*)d_in[10];
  const float* b2  = (const float*)d_in[11];
  const float* Wp1 = (const float*)d_in[12];
  const float* bp1 = (const float*)d_in[13];
  const float* Wp2 = (const float*)d_in[14];
  const float* bp2 = (const float*)d_in[15];

  const int N = in_sizes[0] / 8;     // x is [N, 8]
  const int E = in_sizes[1] / 2;     // edge_index is [2, E]
  const int G = out_size;            // output is [G, 1]
  const int Etot = E + N;
  const int* esrc = ei;
  const int* edst = ei + E;

  char* wsb = (char*)d_ws;
  size_t o = 0;
  auto carve = [&](size_t bytes)->char*{
    char* p = wsb + o; o += (bytes + 255) & ~(size_t)255; return p;
  };
  unsigned short* hproj   = (unsigned short*)carve((size_t)N*HC*sizeof(unsigned short));
  float* a_s      = (float*)carve((size_t)N*HEADS*sizeof(float));
  float* a_d      = (float*)carve((size_t)N*HEADS*sizeof(float));
  float* feat     = (float*)carve((size_t)N*CH*sizeof(float));
  float* wfold    = (float*)carve((size_t)64*8*sizeof(float));
  int*   rowstart = (int*)carve((size_t)N*sizeof(int));
  int*   cursor   = (int*)carve((size_t)N*sizeof(int));
  int*   deg      = (int*)carve((size_t)N*sizeof(int));
  int*   bsum     = (int*)carve((size_t)512*sizeof(int));
  int*   ssrc     = (int*)carve((size_t)Etot*sizeof(int));

  const int eb  = (Etot + 255) / 256;
  const int nb1 = (N + 255) / 256;
  const int ag  = (N + 3) / 4;
  const int atb = (N + 31) / 32;
  const int l1b = 2048;                 // gat_l1: persistent-ish waves
  const int l1w = l1b * 4;

  // ---- CSR build (once; shared by both layers) ----
  hipMemsetAsync(deg, 0, (size_t)N*sizeof(int), stream);
  deg_count_kernel<<<eb, 256, 0, stream>>>(esrc, edst, E, N, deg);
  scan1_kernel<<<nb1, 256, 0, stream>>>(deg, rowstart, bsum, N);
  scan2_kernel<<<1, 512, 0, stream>>>(bsum, nb1);
  scan3_kernel<<<nb1, 256, 0, stream>>>(rowstart, bsum, cursor, N);
  scatter_kernel<<<eb, 256, 0, stream>>>(esrc, edst, E, N, cursor, ssrc);

  // ---- layer 1 (Fin = 8): commuted aggregation, fully fused ----
  fold_kernel<8><<<1, 8*8, 0, stream>>>(W1, as1, ad1, wfold);
  att_kernel<8><<<atb, 256, 0, stream>>>(x, wfold, a_s, a_d, N);
  gat_l1_kernel<<<l1b, 256, 0, stream>>>(rowstart, ssrc, N, Etot, a_s, a_d, x, W1, b1, feat, l1w);

  // ---- layer 2 (Fin = 64) ----
  fold_kernel<64><<<1, 64*8, 0, stream>>>(W2, as2, ad2, wfold);
  att_kernel<64><<<atb, 256, 0, stream>>>(feat, wfold, a_s, a_d, N);
  proj_kernel<64,16><<<(N+15)/16, 256, 0, stream>>>(feat, W2, hproj, N);
  gat_aggregate_kernel<<<ag, 256, 0, stream>>>(rowstart, ssrc, N, Etot, a_s, a_d, hproj, b2, feat);

  // ---- pool + MLP ----
  pool_mlp_kernel<<<G, 256, 0, stream>>>(feat, bat, N, Wp1, bp1, Wp2, bp2, (float*)d_out);
}